// Round 12
// baseline (416.085 us; speedup 1.0000x reference)
//
#include <hip/hip_runtime.h>
#include <hip/hip_bf16.h>
#include <vector>
#include <algorithm>
#include <utility>
#include <stdint.h>

// Problem constants
#define BB 2
#define PP 4096        // H*W
#define FF 288         // C*9
#define KK 32
#define NBASE 32
#define HID 64
#define COUT 64
#define NWG_KM 32      // k-means workgroups (16 per batch)
#define SUBS 16
#define OUT_ELEMS 524288   // 2*64*4096; idx chunk follows

#define THREEFRY_PARTITIONABLE 1

typedef unsigned short u16;

// ---------------- ws layout (bytes) ----------------
// [64..67] dtype flag (written by kDetect)
#define OFF_IDX    512          // 2*4096*4  = 32768
#define OFF_ATTN   33280        // 64*32*4   = 8192
#define OFF_BIAS   41472        // 64*64*4   = 16384
#define OFF_PART   57856        // 4 slots * 16 subs * 1024 f32 = 262144 -> 320000
#define OFF_CNTS   320000       // 4 slots * 16 subs * 32 f32   = 8192   -> 328192
#define OFF_CPART  328192       // 32 chunks * 32 k * 289 f32 = 1183744 -> 1511936
#define OFF_WG     1511936      // 64*64*288 u16 (b,k,cout,f) = 2359296 -> 3871232
#define OFF_BAR2   3871232      // slots 32*16 ints (2048) + gen (4); memset 4096

struct InitIdx { int v[2][32]; };

// ---------------- device helpers ----------------
__device__ __forceinline__ float bf2f(u16 u){
  union { unsigned int i; float f; } cv; cv.i = ((unsigned int)u) << 16; return cv.f;
}
__device__ __forceinline__ u16 f2bf(float f){
  union { float f; unsigned int i; } cv; cv.f = f;
  unsigned int x = cv.i;
  unsigned int r = (x + 0x7FFFu + ((x >> 16) & 1u)) >> 16;
  return (u16)r;
}
__device__ __forceinline__ float u_lo(unsigned int u){
  union { unsigned int i; float f; } cv; cv.i = u << 16; return cv.f;
}
__device__ __forceinline__ float u_hi(unsigned int u){
  union { unsigned int i; float f; } cv; cv.i = u & 0xFFFF0000u; return cv.f;
}

template<bool BF>
__device__ __forceinline__ float ld(const void* p, size_t i){
  if constexpr (BF) { return bf2f(((const u16*)p)[i]); }
  else              { return ((const float*)p)[i]; }
}
template<bool BF>
__device__ __forceinline__ void st(void* p, size_t i, float v){
  if constexpr (BF) { ((u16*)p)[i] = f2bf(v); }
  else              { ((float*)p)[i] = v; }
}

template<bool BF>
__device__ __forceinline__ float obs_chan(const void* x, size_t bi, int h, int w){
  float s = 0.f;
  #pragma unroll
  for (int dh=-1; dh<=1; ++dh){
    int hh = h + dh;
    #pragma unroll
    for (int dw=-1; dw<=1; ++dw){
      int ww = w + dw;
      float v = 0.f;
      if ((unsigned)hh < 64u && (unsigned)ww < 64u) v = ld<BF>(x, bi + (hh<<6) + ww);
      s += v;
    }
  }
  return s / 9.0f;
}

// Flag-tree grid barrier (R9-verified)
__device__ __forceinline__ void gbar2(int* slots, int* gen, int nwg, int epoch){
  __syncthreads();
  __threadfence();
  const int t = threadIdx.x;
  const int wg = blockIdx.x;
  if (t == 0)
    __hip_atomic_store(&slots[wg*16], epoch, __ATOMIC_RELEASE, __HIP_MEMORY_SCOPE_AGENT);
  if (wg == 0){
    if (t < nwg){
      while (__hip_atomic_load(&slots[t*16], __ATOMIC_ACQUIRE, __HIP_MEMORY_SCOPE_AGENT) < epoch){}
    }
    __syncthreads();
    if (t == 0)
      __hip_atomic_store(gen, epoch, __ATOMIC_RELEASE, __HIP_MEMORY_SCOPE_AGENT);
  }
  if (t == 0){
    while (__hip_atomic_load(gen, __ATOMIC_ACQUIRE, __HIP_MEMORY_SCOPE_AGENT) < epoch){}
  }
  __syncthreads();
  __threadfence();
}

// ---------------- Kernel 0: input dtype detection (verified) ----------------
__global__ __launch_bounds__(256) void kDetect(const void* __restrict__ x, int* flag){
  __shared__ int cnt;
  if (threadIdx.x == 0) cnt = 0;
  __syncthreads();
  const u16* p = (const u16*)x;
  int bad = 0;
  for (int i = threadIdx.x; i < 1024; i += 256){
    u16 u = p[2*i];
    unsigned e = (u >> 7) & 0xFFu;
    if (e >= 131u) ++bad;
  }
  atomicAdd(&cnt, bad);
  __syncthreads();
  if (threadIdx.x == 0) *flag = (cnt < 102) ? 1 : 0;
}

// ---------------- Kernel B: persistent k-means ----------------
// Change under test (hardened): (1) run-accumulated partial sums over transposed
// obsT (aligned, scalar a_loc reads), (2) 4-way k-interleaved assignment dots.
// Per-k fma order unchanged -> idx bit-identical to R8/R9.
#define OBST_STRIDE 264

template<bool BF>
__device__ void kB_body(const void* __restrict__ x,
                        float* __restrict__ part,
                        float* __restrict__ cnts,
                        int* __restrict__ idxg,
                        void* __restrict__ dout,
                        int* __restrict__ slots,
                        int* __restrict__ gen,
                        const InitIdx& ii){
  const int t   = threadIdx.x;
  const int wg  = blockIdx.x;
  const int mb  = wg >> 4;
  const int sub = wg & 15;
  const int pg  = sub*256 + t;

  __shared__ __align__(16) float obsT[32*OBST_STRIDE];   // [d][p], stride 264
  __shared__ __align__(16) float cent[2][32][32];
  __shared__ float cc_s[32];
  __shared__ int   a_loc[256];
  __shared__ float sq[32][32];
  __shared__ float snorm[32];
  __shared__ float cntsh[32];

  float o[32];
  {
    int h = pg >> 6, w = pg & 63;
    size_t xb = (size_t)mb << 17;
    for (int c=0; c<32; ++c){
      float v = obs_chan<BF>(x, xb + ((size_t)c<<12), h, w);
      o[c] = v; obsT[c*OBST_STRIDE + t] = v;
    }
  }
  if (t < 64){
    int bb = t >> 5, j = t & 31;
    int q = ii.v[bb][j];
    int qh = q >> 6, qw = q & 63;
    size_t xq = (size_t)bb << 17;
    for (int c=0; c<32; ++c) cent[bb][j][c] = obs_chan<BF>(x, xq + ((size_t)c<<12), qh, qw);
  }
  __syncthreads();

  float ss = 0.f;
  #pragma unroll
  for (int d=0; d<32; ++d) ss = fmaf(o[d], o[d], ss);

  const int d = t & 31, g = t >> 5;

  bool act0 = true, act1 = true;
  int parity = 0;

  for (int it=0; it<20; ++it){
    if (!(act0 || act1)) break;
    bool mine = (mb==0) ? act0 : act1;
    if (mine){
      if (t < 32){
        float s = 0.f;
        #pragma unroll
        for (int dd=0; dd<32; ++dd){ float v = cent[mb][t][dd]; s = fmaf(v,v,s); }
        cc_s[t] = s;
      }
      __syncthreads();
      // assignment: 4-way k-interleave, per-k dot order o[0]..o[31] (frozen)
      float best = 3.0e38f; int bk = 0;
      for (int k=0; k<32; k+=4){
        const float4* c0 = (const float4*)&cent[mb][k  ][0];
        const float4* c1 = (const float4*)&cent[mb][k+1][0];
        const float4* c2 = (const float4*)&cent[mb][k+2][0];
        const float4* c3 = (const float4*)&cent[mb][k+3][0];
        float dt0=0.f, dt1=0.f, dt2=0.f, dt3=0.f;
        #pragma unroll
        for (int q=0; q<8; ++q){
          float4 a0 = c0[q], a1 = c1[q], a2 = c2[q], a3 = c3[q];
          float o0 = o[q*4+0], o1 = o[q*4+1], o2 = o[q*4+2], o3 = o[q*4+3];
          dt0 = fmaf(o0,a0.x,dt0); dt0 = fmaf(o1,a0.y,dt0); dt0 = fmaf(o2,a0.z,dt0); dt0 = fmaf(o3,a0.w,dt0);
          dt1 = fmaf(o0,a1.x,dt1); dt1 = fmaf(o1,a1.y,dt1); dt1 = fmaf(o2,a1.z,dt1); dt1 = fmaf(o3,a1.w,dt1);
          dt2 = fmaf(o0,a2.x,dt2); dt2 = fmaf(o1,a2.y,dt2); dt2 = fmaf(o2,a2.z,dt2); dt2 = fmaf(o3,a2.w,dt2);
          dt3 = fmaf(o0,a3.x,dt3); dt3 = fmaf(o1,a3.y,dt3); dt3 = fmaf(o2,a3.z,dt3); dt3 = fmaf(o3,a3.w,dt3);
        }
        float di0 = (ss - 2.0f*dt0) + cc_s[k];
        float di1 = (ss - 2.0f*dt1) + cc_s[k+1];
        float di2 = (ss - 2.0f*dt2) + cc_s[k+2];
        float di3 = (ss - 2.0f*dt3) + cc_s[k+3];
        if (di0 < best){ best = di0; bk = k; }
        if (di1 < best){ best = di1; bk = k+1; }
        if (di2 < best){ best = di2; bk = k+2; }
        if (di3 < best){ best = di3; bk = k+3; }
      }
      a_loc[t] = bk;
      __syncthreads();
      // run-accumulated partial sums (p order preserved within runs)
      float s0=0.f, s1=0.f, s2=0.f, s3=0.f;
      float cntv = 0.f;
      float racc = 0.f; int runlen = 0;
      int kcur = a_loc[0];
      const float* orow = &obsT[d*OBST_STRIDE];
      auto kflush = [&](){
        bool mine_ = ((kcur & 7) == g);
        int j_ = kcur >> 3;
        if (j_ == 0){ if (mine_) s0 += racc; }
        else if (j_ == 1){ if (mine_) s1 += racc; }
        else if (j_ == 2){ if (mine_) s2 += racc; }
        else { if (mine_) s3 += racc; }
        if (t == kcur) cntv += (float)runlen;
        racc = 0.f; runlen = 0;
      };
      for (int p4=0; p4<256; p4+=4){
        int a0 = a_loc[p4+0], a1 = a_loc[p4+1], a2 = a_loc[p4+2], a3 = a_loc[p4+3];
        float4 v4 = *(const float4*)&orow[p4];
        if (a0==kcur && a1==kcur && a2==kcur && a3==kcur){
          racc += v4.x; racc += v4.y; racc += v4.z; racc += v4.w;
          runlen += 4;
        } else {
          if (a0 != kcur){ kflush(); kcur = a0; }
          racc += v4.x; ++runlen;
          if (a1 != kcur){ kflush(); kcur = a1; }
          racc += v4.y; ++runlen;
          if (a2 != kcur){ kflush(); kcur = a2; }
          racc += v4.z; ++runlen;
          if (a3 != kcur){ kflush(); kcur = a3; }
          racc += v4.w; ++runlen;
        }
      }
      kflush();
      float* Pg = part + ((size_t)((parity*2 + mb)*SUBS + sub))*1024;
      Pg[(g    )*32 + d] = s0;
      Pg[(g+ 8 )*32 + d] = s1;
      Pg[(g+16 )*32 + d] = s2;
      Pg[(g+24 )*32 + d] = s3;
      if (t < 32)
        cnts[((size_t)((parity*2 + mb)*SUBS + sub))*32 + t] = cntv;
    }
    gbar2(slots, gen, NWG_KM, it+1);
    for (int bb=0; bb<2; ++bb){
      bool ab = (bb==0) ? act0 : act1;
      if (!ab) continue;
      const float* Pb = part + (size_t)((parity*2 + bb)*SUBS)*1024;
      const float* Cb = cnts + (size_t)((parity*2 + bb)*SUBS)*32;
      if (t < 32){
        float s = 0.f;
        for (int si=0; si<SUBS; ++si) s += Cb[si*32 + t];
        cntsh[t] = s;
      }
      __syncthreads();
      {
        int k = t >> 3, d4 = (t & 7) * 4;
        float4 v = make_float4(0.f, 0.f, 0.f, 0.f);
        for (int si=0; si<SUBS; ++si){
          const float4 p4 = *(const float4*)&Pb[si*1024 + k*32 + d4];
          v.x += p4.x; v.y += p4.y; v.z += p4.z; v.w += p4.w;
        }
        float cn = cntsh[k];
        float den = fmaxf(cn, 1.f);
        bool pos = cn > 0.f;
        float o0 = cent[bb][k][d4+0], o1 = cent[bb][k][d4+1];
        float o2 = cent[bb][k][d4+2], o3 = cent[bb][k][d4+3];
        float n0 = pos ? (v.x / den) : o0;
        float n1 = pos ? (v.y / den) : o1;
        float n2 = pos ? (v.z / den) : o2;
        float n3 = pos ? (v.w / den) : o3;
        float e0 = n0-o0, e1 = n1-o1, e2 = n2-o2, e3 = n3-o3;
        sq[k][d4+0] = e0*e0; sq[k][d4+1] = e1*e1;
        sq[k][d4+2] = e2*e2; sq[k][d4+3] = e3*e3;
        cent[bb][k][d4+0] = n0; cent[bb][k][d4+1] = n1;
        cent[bb][k][d4+2] = n2; cent[bb][k][d4+3] = n3;
      }
      __syncthreads();
      if (t < 32){
        float s = 0.f;
        #pragma unroll
        for (int dd=0; dd<32; ++dd) s += sq[t][dd];
        snorm[t] = sqrtf(s);
      }
      __syncthreads();
      float sh = 0.f;
      for (int k=0;k<32;++k) sh += snorm[k];
      bool na = ((it+1) < 20) && ((double)sh >= 20.48);
      if (bb==0) act0 = na; else act1 = na;
      __syncthreads();
    }
    parity ^= 1;
  }
  __syncthreads();
  if (t < 32){
    float s = 0.f;
    #pragma unroll
    for (int dd=0; dd<32; ++dd){ float v = cent[mb][t][dd]; s = fmaf(v,v,s); }
    cc_s[t] = s;
  }
  __syncthreads();
  float best = 3.0e38f; int bk = 0;
  for (int k=0; k<32; k+=4){
    const float4* c0 = (const float4*)&cent[mb][k  ][0];
    const float4* c1 = (const float4*)&cent[mb][k+1][0];
    const float4* c2 = (const float4*)&cent[mb][k+2][0];
    const float4* c3 = (const float4*)&cent[mb][k+3][0];
    float dt0=0.f, dt1=0.f, dt2=0.f, dt3=0.f;
    #pragma unroll
    for (int q=0; q<8; ++q){
      float4 a0 = c0[q], a1 = c1[q], a2 = c2[q], a3 = c3[q];
      float o0 = o[q*4+0], o1 = o[q*4+1], o2 = o[q*4+2], o3 = o[q*4+3];
      dt0 = fmaf(o0,a0.x,dt0); dt0 = fmaf(o1,a0.y,dt0); dt0 = fmaf(o2,a0.z,dt0); dt0 = fmaf(o3,a0.w,dt0);
      dt1 = fmaf(o0,a1.x,dt1); dt1 = fmaf(o1,a1.y,dt1); dt1 = fmaf(o2,a1.z,dt1); dt1 = fmaf(o3,a1.w,dt1);
      dt2 = fmaf(o0,a2.x,dt2); dt2 = fmaf(o1,a2.y,dt2); dt2 = fmaf(o2,a2.z,dt2); dt2 = fmaf(o3,a2.w,dt2);
      dt3 = fmaf(o0,a3.x,dt3); dt3 = fmaf(o1,a3.y,dt3); dt3 = fmaf(o2,a3.z,dt3); dt3 = fmaf(o3,a3.w,dt3);
    }
    float di0 = (ss - 2.0f*dt0) + cc_s[k];
    float di1 = (ss - 2.0f*dt1) + cc_s[k+1];
    float di2 = (ss - 2.0f*dt2) + cc_s[k+2];
    float di3 = (ss - 2.0f*dt3) + cc_s[k+3];
    if (di0 < best){ best = di0; bk = k; }
    if (di1 < best){ best = di1; bk = k+1; }
    if (di2 < best){ best = di2; bk = k+2; }
    if (di3 < best){ best = di3; bk = k+3; }
  }
  idxg[mb*PP + pg] = bk;
  st<BF>(dout, (size_t)OUT_ELEMS + mb*PP + pg, (float)bk);
}

__global__ __launch_bounds__(256) void kB(const void* x, float* part, float* cnts,
                                          int* idxg, void* dout,
                                          int* slots, int* gen,
                                          const int* flag, InitIdx ii){
  if (*flag) kB_body<true >(x, part, cnts, idxg, dout, slots, gen, ii);
  else       kB_body<false>(x, part, cnts, idxg, dout, slots, gen, ii);
}

// ---------------- Kernel C v4: run-accumulated cluster patch sums (R8-verified) ------------
template<bool BF>
__device__ void kC_body(const void* __restrict__ x,
                        const int* __restrict__ idxg,
                        float* __restrict__ cpart,
                        float* __restrict__ acc,    // [32*289]
                        int* __restrict__ icnt,     // [32]
                        int* __restrict__ idxsh){   // [256]
  int cg = blockIdx.x;            // 0..31
  int b = cg >> 4, pc = cg & 15;
  int t = threadIdx.x, wv = t >> 6, lane = t & 63;
  for (int e=t; e<32*289; e+=256) acc[e] = 0.f;
  if (t < 32) icnt[t] = 0;
  idxsh[t] = idxg[b*PP + pc*256 + t];
  __syncthreads();
  atomicAdd(&icnt[idxsh[t]], 1);

  int f0 = wv*72 + lane;
  int f1 = wv*72 + 64 + lane;
  bool has1 = lane < 8;
  int c0 = f0/9, j0 = f0%9, dh0 = j0/3 - 1, dw0 = j0%3 - 1;
  int c1 = f1/9, j1 = f1%9, dh1 = j1/3 - 1, dw1 = j1%3 - 1;
  size_t xb = (size_t)b << 17;

  float v0 = 0.f, v1 = 0.f; int kcur = -1;
  for (int i=0; i<256; ++i){
    int k = idxsh[i];
    if (k != kcur){
      if (kcur >= 0){
        acc[kcur*289 + f0] += v0;
        if (has1) acc[kcur*289 + f1] += v1;
      }
      v0 = 0.f; v1 = 0.f; kcur = k;
    }
    int h = (pc << 2) + (i >> 6), w_ = i & 63;
    int hh0 = h + dh0, ww0 = w_ + dw0;
    if ((unsigned)hh0 < 64u && (unsigned)ww0 < 64u)
      v0 += ld<BF>(x, xb + ((size_t)c0 << 12) + (hh0 << 6) + ww0);
    if (has1){
      int hh1 = h + dh1, ww1 = w_ + dw1;
      if ((unsigned)hh1 < 64u && (unsigned)ww1 < 64u)
        v1 += ld<BF>(x, xb + ((size_t)c1 << 12) + (hh1 << 6) + ww1);
    }
  }
  acc[kcur*289 + f0] += v0;
  if (has1) acc[kcur*289 + f1] += v1;
  __syncthreads();
  float* cp = cpart + (size_t)cg*(32*289);
  for (int e=t; e<32*289; e+=256){
    int r = e % 289;
    cp[e] = (r == 288) ? (float)icnt[e/289] : acc[e];
  }
}

__global__ __launch_bounds__(256) void kC(const void* x, const int* idxg,
                                          float* cpart, const int* flag){
  __shared__ float acc[32*289];
  __shared__ int   icnt[32];
  __shared__ int   idxsh[256];
  if (*flag) kC_body<true >(x, idxg, cpart, acc, icnt, idxsh);
  else       kC_body<false>(x, idxg, cpart, acc, icnt, idxsh);
}

// ---------------- Kernel D: merge partials -> centers + 2 MLPs + softmax (verified) --------
template<bool BF>
__device__ void kD_body(const float* __restrict__ cpart,
                        const void* kg_w1, const void* kg_b1,
                        const void* kg_w2, const void* kg_b2,
                        const void* kg_w3, const void* kg_b3,
                        const void* bg_w1, const void* bg_b1,
                        const void* bg_w2, const void* bg_b2,
                        const void* bg_w3, const void* bg_b3,
                        float* __restrict__ attn,
                        float* __restrict__ biasO,
                        float* __restrict__ row,
                        float* __restrict__ h1,
                        float* __restrict__ h2,
                        float* __restrict__ lgs){
  int wg = blockIdx.x; int b = wg >> 5; int k = wg & 31;
  int t = threadIdx.x;   // 64 threads
  float cnt = 0.f;
  for (int ch=0; ch<16; ++ch)
    cnt += cpart[((size_t)(b*16+ch)*32 + k)*289 + 288];
  float den = fmaxf(cnt, 1.f);
  for (int f=t; f<FF; f+=64){
    float s = 0.f;
    for (int ch=0; ch<16; ++ch)
      s += cpart[((size_t)(b*16+ch)*32 + k)*289 + f];
    row[f] = s / den;
  }
  __syncthreads();

  {
    float s = 0.f;
    #pragma unroll 8
    for (int f=0; f<FF; ++f) s = fmaf(row[f], ld<BF>(kg_w1, f*HID + t), s);
    h1[t] = fmaxf(s + ld<BF>(kg_b1, t), 0.f);
  }
  __syncthreads();
  {
    float s = 0.f;
    #pragma unroll 8
    for (int h=0; h<HID; ++h) s = fmaf(h1[h], ld<BF>(kg_w2, h*HID + t), s);
    h2[t] = fmaxf(s + ld<BF>(kg_b2, t), 0.f);
  }
  __syncthreads();
  if (t < 32){
    float s = 0.f;
    #pragma unroll 8
    for (int h=0; h<HID; ++h) s = fmaf(h2[h], ld<BF>(kg_w3, h*NBASE + t), s);
    lgs[t] = s + ld<BF>(kg_b3, t);
  }
  __syncthreads();
  if (t < 32){
    float mx = -3.0e38f;
    for (int i=0;i<NBASE;++i) mx = fmaxf(mx, lgs[i]);
    float se = 0.f;
    for (int i=0;i<NBASE;++i) se += expf(lgs[i]-mx);
    attn[wg*NBASE + t] = expf(lgs[t]-mx) / se;
  }
  __syncthreads();
  {
    float s = 0.f;
    #pragma unroll 8
    for (int f=0; f<FF; ++f) s = fmaf(row[f], ld<BF>(bg_w1, f*HID + t), s);
    h1[t] = fmaxf(s + ld<BF>(bg_b1, t), 0.f);
  }
  __syncthreads();
  {
    float s = 0.f;
    #pragma unroll 8
    for (int h=0; h<HID; ++h) s = fmaf(h1[h], ld<BF>(bg_w2, h*HID + t), s);
    h2[t] = fmaxf(s + ld<BF>(bg_b2, t), 0.f);
  }
  __syncthreads();
  {
    float s = 0.f;
    #pragma unroll 8
    for (int h=0; h<HID; ++h) s = fmaf(h2[h], ld<BF>(bg_w3, h*COUT + t), s);
    biasO[wg*COUT + t] = s + ld<BF>(bg_b3, t);
  }
}

__global__ __launch_bounds__(64) void kD(const float* cpart,
                                         const void* kg_w1, const void* kg_b1,
                                         const void* kg_w2, const void* kg_b2,
                                         const void* kg_w3, const void* kg_b3,
                                         const void* bg_w1, const void* bg_b1,
                                         const void* bg_w2, const void* bg_b2,
                                         const void* bg_w3, const void* bg_b3,
                                         float* attn, float* biasO, const int* flag){
  __shared__ float row[FF];
  __shared__ float h1[64];
  __shared__ float h2[64];
  __shared__ float lgs[32];
  if (*flag) kD_body<true >(cpart, kg_w1,kg_b1,kg_w2,kg_b2,kg_w3,kg_b3,
                            bg_w1,bg_b1,bg_w2,bg_b2,bg_w3,bg_b3, attn, biasO, row,h1,h2,lgs);
  else       kD_body<false>(cpart, kg_w1,kg_b1,kg_w2,kg_b2,kg_w3,kg_b3,
                            bg_w1,bg_b1,bg_w2,bg_b2,bg_w3,bg_b3, attn, biasO, row,h1,h2,lgs);
}

// ---------------- Kernel E: Wg[b][k][cout][f] (bf16) = sum_n attn*base (verified) ----------
template<bool BF>
__device__ void kE_body(const void* __restrict__ base,
                        const float* __restrict__ attn,
                        u16* __restrict__ Wg,
                        float* __restrict__ at,
                        float* __restrict__ tile){   // [72][65]
  int wg = blockIdx.x;
  int fq = wg & 3, bk = wg >> 2;
  int t = threadIdx.x;
  if (t < 32) at[t] = attn[bk*NBASE + t];
  __syncthreads();
  int f0 = fq*72;
  for (int e=t; e<72*64; e+=256){
    int fl = e >> 6, c = e & 63;
    size_t bi = (size_t)(f0 + fl)*COUT + c;
    float s = 0.f;
    #pragma unroll 8
    for (int n=0; n<NBASE; ++n)
      s = fmaf(at[n], ld<BF>(base, bi + (size_t)n*FF*COUT), s);
    tile[fl*65 + c] = s;
  }
  __syncthreads();
  for (int e=t; e<72*64; e+=256){
    int c = e / 72, fl = e % 72;
    Wg[(size_t)bk*(64*FF) + (size_t)c*FF + f0 + fl] = f2bf(tile[fl*65 + c]);
  }
}

__global__ __launch_bounds__(256) void kE(const void* base, const float* attn,
                                          u16* Wg, const int* flag){
  __shared__ float at[32];
  __shared__ float tile[72*65];
  if (*flag) kE_body<true >(base, attn, Wg, at, tile);
  else       kE_body<false>(base, attn, Wg, at, tile);
}

// ---------------- Kernel F: conv (R5 structure, verified) ----------------
template<bool BF>
__device__ void kF_body(const void* __restrict__ x,
                        const int* __restrict__ idxg,
                        const u16* __restrict__ Wg,
                        const float* __restrict__ biasO,
                        void* __restrict__ dout,
                        u16* __restrict__ patch,    // [16][296]
                        float* __restrict__ outT){  // [64][17]
  int wg = blockIdx.x;
  int q = wg & 3, h = (wg >> 2) & 63, b = wg >> 8;
  int t = threadIdx.x, wv = t >> 6, lane = t & 63;
  int w0 = q << 4;

  for (int e=t; e<16*FF; e+=256){
    int pl = e & 15, fe = e >> 4;
    int c = fe / 9, j = fe % 9;
    int hh = h + j/3 - 1, ww = w0 + pl + (j%3) - 1;
    float v = 0.f;
    if ((unsigned)hh < 64u && (unsigned)ww < 64u)
      v = ld<BF>(x, ((size_t)b << 17) + ((size_t)c << 12) + (hh<<6) + ww);
    patch[pl*296 + fe] = f2bf(v);
  }
  __syncthreads();

  #pragma unroll
  for (int i=0; i<4; ++i){
    int pl = (wv << 2) + i;
    int p = (h << 6) + w0 + pl;
    int k = idxg[(b << 12) + p];
    const uint4* Wp = (const uint4*)(Wg + ((size_t)((b << 5) + k)*64 + lane)*FF);
    const uint4* Pp = (const uint4*)(patch + pl*296);
    float acc = 0.f;
    #pragma unroll 6
    for (int j=0; j<36; ++j){
      uint4 wv4 = Wp[j];
      uint4 pv4 = Pp[j];
      acc = fmaf(u_lo(pv4.x), u_lo(wv4.x), acc);
      acc = fmaf(u_hi(pv4.x), u_hi(wv4.x), acc);
      acc = fmaf(u_lo(pv4.y), u_lo(wv4.y), acc);
      acc = fmaf(u_hi(pv4.y), u_hi(wv4.y), acc);
      acc = fmaf(u_lo(pv4.z), u_lo(wv4.z), acc);
      acc = fmaf(u_hi(pv4.z), u_hi(wv4.z), acc);
      acc = fmaf(u_lo(pv4.w), u_lo(wv4.w), acc);
      acc = fmaf(u_hi(pv4.w), u_hi(wv4.w), acc);
    }
    float bias = biasO[((b << 5) + k)*COUT + lane];
    outT[lane*17 + pl] = acc + bias;
  }
  __syncthreads();

  for (int e=t; e<1024; e+=256){
    int cout = e >> 4, pl = e & 15;
    st<BF>(dout, (((size_t)(b << 6) + cout) << 12) + (h << 6) + w0 + pl,
           outT[cout*17 + pl]);
  }
}

__global__ __launch_bounds__(256) void kF(const void* x, const int* idxg,
                                          const u16* Wg, const float* biasO,
                                          void* dout, const int* flag){
  __shared__ u16   patch[16*296];
  __shared__ float outT[64*17];
  if (*flag) kF_body<true >(x, idxg, Wg, biasO, dout, patch, outT);
  else       kF_body<false>(x, idxg, Wg, biasO, dout, patch, outT);
}

// ---------------- host: JAX threefry2x32 + permutation(key,4096)[:32] ----------------
static inline uint32_t rotl32(uint32_t x, int d){ return (x<<d)|(x>>(32-d)); }
static void tf_block(uint32_t k0,uint32_t k1,uint32_t x0,uint32_t x1,uint32_t&o0,uint32_t&o1){
  uint32_t ks2 = k0 ^ k1 ^ 0x1BD11BDAu;
  uint32_t v0 = x0 + k0, v1 = x1 + k1;
  const int ra[4]={13,15,26,6}, rb[4]={17,29,16,24};
  #define R4(r) for(int i_=0;i_<4;++i_){ v0 += v1; v1 = rotl32(v1,(r)[i_]); v1 ^= v0; }
  R4(ra); v0 += k1;  v1 += ks2 + 1u;
  R4(rb); v0 += ks2; v1 += k0  + 2u;
  R4(ra); v0 += k0;  v1 += k1  + 3u;
  R4(rb); v0 += k1;  v1 += ks2 + 4u;
  R4(ra); v0 += ks2; v1 += k0  + 5u;
  #undef R4
  o0 = v0; o1 = v1;
}
struct KP{ uint32_t a, b; };
static void tf_split(KP k, KP& first, KP& second){
#if THREEFRY_PARTITIONABLE
  uint32_t a0,b0,a1,b1;
  tf_block(k.a,k.b, 0u,0u, a0,b0);
  tf_block(k.a,k.b, 0u,1u, a1,b1);
  first  = KP{a0,b0};
  second = KP{a1,b1};
#else
  uint32_t a0,b0,a1,b1;
  tf_block(k.a,k.b, 0u,2u, a0,b0);
  tf_block(k.a,k.b, 1u,3u, a1,b1);
  first  = KP{a0,a1};
  second = KP{b0,b1};
#endif
}
static void random_bits_4096(KP k, std::vector<uint32_t>& bits){
#if THREEFRY_PARTITIONABLE
  for (int i=0;i<4096;++i){
    uint32_t o0,o1; tf_block(k.a,k.b, 0u,(uint32_t)i, o0,o1);
    bits[i] = o0 ^ o1;
  }
#else
  for (int i=0;i<2048;++i){
    uint32_t o0,o1; tf_block(k.a,k.b,(uint32_t)i,(uint32_t)(i+2048),o0,o1);
    bits[i] = o0; bits[i+2048] = o1;
  }
#endif
}
static void perm_first32(KP key, int* out32){
  std::vector<int> vals(4096);
  for (int i=0;i<4096;++i) vals[i] = i;
  std::vector<uint32_t> bits(4096);
  std::vector<std::pair<uint32_t,int>> pr(4096);
  KP k = key;
  for (int r=0;r<2;++r){
    KP nk, sk; tf_split(k, nk, sk); k = nk;
    random_bits_4096(sk, bits);
    for (int i=0;i<4096;++i) pr[i] = std::make_pair(bits[i], vals[i]);
    std::stable_sort(pr.begin(), pr.end(),
        [](const std::pair<uint32_t,int>& a, const std::pair<uint32_t,int>& c){ return a.first < c.first; });
    for (int i=0;i<4096;++i) vals[i] = pr[i].second;
  }
  for (int j=0;j<32;++j) out32[j] = vals[j];
}

extern "C" void kernel_launch(void* const* d_in, const int* in_sizes, int n_in,
                              void* d_out, int out_size, void* d_ws, size_t ws_size,
                              hipStream_t stream) {
  const void* x     = d_in[0];
  const void* base  = d_in[1];
  const void* kg_w1 = d_in[2];
  const void* kg_b1 = d_in[3];
  const void* kg_w2 = d_in[4];
  const void* kg_b2 = d_in[5];
  const void* kg_w3 = d_in[6];
  const void* kg_b3 = d_in[7];
  const void* bg_w1 = d_in[8];
  const void* bg_b1 = d_in[9];
  const void* bg_w2 = d_in[10];
  const void* bg_b2 = d_in[11];
  const void* bg_w3 = d_in[12];
  const void* bg_b3 = d_in[13];

  char* ws = (char*)d_ws;
  int*   flag  = (int*)(ws + 64);
  int*   idxg  = (int*)(ws + OFF_IDX);
  float* attn  = (float*)(ws + OFF_ATTN);
  float* biasO = (float*)(ws + OFF_BIAS);
  float* part  = (float*)(ws + OFF_PART);
  float* cnts  = (float*)(ws + OFF_CNTS);
  float* cpart = (float*)(ws + OFF_CPART);
  u16*   Wg    = (u16*)(ws + OFF_WG);
  int*   slots = (int*)(ws + OFF_BAR2);
  int*   gen   = (int*)(ws + OFF_BAR2 + 2048);

  InitIdx ii;
  KP root = KP{0u, 42u};
  KP kb0, kb1; tf_split(root, kb0, kb1);
  perm_first32(kb0, ii.v[0]);
  perm_first32(kb1, ii.v[1]);

  hipMemsetAsync(ws + OFF_BAR2, 0, 4096, stream);   // barrier slots + gen

  kDetect<<<1, 256, 0, stream>>>(x, flag);
  kB<<<NWG_KM, 256, 0, stream>>>(x, part, cnts, idxg, d_out, slots, gen, flag, ii);
  kC<<<32, 256, 0, stream>>>(x, idxg, cpart, flag);
  kD<<<64, 64, 0, stream>>>(cpart,
                            kg_w1, kg_b1, kg_w2, kg_b2, kg_w3, kg_b3,
                            bg_w1, bg_b1, bg_w2, bg_b2, bg_w3, bg_b3,
                            attn, biasO, flag);
  kE<<<256, 256, 0, stream>>>(base, attn, Wg, flag);
  kF<<<512, 256, 0, stream>>>(x, idxg, Wg, biasO, d_out, flag);
}

// Round 14
// 390.873 us; speedup vs baseline: 1.0645x; 1.0645x over previous
//
#include <hip/hip_runtime.h>
#include <hip/hip_bf16.h>
#include <vector>
#include <algorithm>
#include <utility>
#include <stdint.h>

// Problem constants
#define BB 2
#define PP 4096        // H*W
#define FF 288         // C*9
#define KK 32
#define NBASE 32
#define HID 64
#define COUT 64
#define NWG_KM 32      // k-means workgroups (16 per batch)
#define SUBS 16
#define OUT_ELEMS 524288   // 2*64*4096; idx chunk follows

#define THREEFRY_PARTITIONABLE 1

typedef unsigned short u16;

// ---------------- ws layout (bytes) ----------------
// [64..67] dtype flag (written by kDetect)
#define OFF_IDX    512          // 2*4096*4  = 32768
#define OFF_ATTN   33280        // 64*32*4   = 8192
#define OFF_BIAS   41472        // 64*64*4   = 16384
#define OFF_PART   57856        // 4 slots * 16 subs * 1024 f32 = 262144 -> 320000
#define OFF_CNTS   320000       // 4 slots * 16 subs * 32 f32   = 8192   -> 328192
#define OFF_CPART  328192       // 32 chunks * 32 k * 289 f32 = 1183744 -> 1511936
#define OFF_WG     1511936      // 64*64*288 u16 (b,k,cout,f) = 2359296 -> 3871232
#define OFF_BAR2   3871232      // slots 32*16 ints (2048) + gen (4); memset 4096

struct InitIdx { int v[2][32]; };

// ---------------- device helpers ----------------
__device__ __forceinline__ float bf2f(u16 u){
  union { unsigned int i; float f; } cv; cv.i = ((unsigned int)u) << 16; return cv.f;
}
__device__ __forceinline__ u16 f2bf(float f){
  union { float f; unsigned int i; } cv; cv.f = f;
  unsigned int x = cv.i;
  unsigned int r = (x + 0x7FFFu + ((x >> 16) & 1u)) >> 16;
  return (u16)r;
}
__device__ __forceinline__ float u_lo(unsigned int u){
  union { unsigned int i; float f; } cv; cv.i = u << 16; return cv.f;
}
__device__ __forceinline__ float u_hi(unsigned int u){
  union { unsigned int i; float f; } cv; cv.i = u & 0xFFFF0000u; return cv.f;
}

template<bool BF>
__device__ __forceinline__ float ld(const void* p, size_t i){
  if constexpr (BF) { return bf2f(((const u16*)p)[i]); }
  else              { return ((const float*)p)[i]; }
}
template<bool BF>
__device__ __forceinline__ void st(void* p, size_t i, float v){
  if constexpr (BF) { ((u16*)p)[i] = f2bf(v); }
  else              { ((float*)p)[i] = v; }
}

template<bool BF>
__device__ __forceinline__ float obs_chan(const void* x, size_t bi, int h, int w){
  float s = 0.f;
  #pragma unroll
  for (int dh=-1; dh<=1; ++dh){
    int hh = h + dh;
    #pragma unroll
    for (int dw=-1; dw<=1; ++dw){
      int ww = w + dw;
      float v = 0.f;
      if ((unsigned)hh < 64u && (unsigned)ww < 64u) v = ld<BF>(x, bi + (hh<<6) + ww);
      s += v;
    }
  }
  return s / 9.0f;
}

// Flag-tree grid barrier (R9-verified)
__device__ __forceinline__ void gbar2(int* slots, int* gen, int nwg, int epoch){
  __syncthreads();
  __threadfence();
  const int t = threadIdx.x;
  const int wg = blockIdx.x;
  if (t == 0)
    __hip_atomic_store(&slots[wg*16], epoch, __ATOMIC_RELEASE, __HIP_MEMORY_SCOPE_AGENT);
  if (wg == 0){
    if (t < nwg){
      while (__hip_atomic_load(&slots[t*16], __ATOMIC_ACQUIRE, __HIP_MEMORY_SCOPE_AGENT) < epoch){}
    }
    __syncthreads();
    if (t == 0)
      __hip_atomic_store(gen, epoch, __ATOMIC_RELEASE, __HIP_MEMORY_SCOPE_AGENT);
  }
  if (t == 0){
    while (__hip_atomic_load(gen, __ATOMIC_ACQUIRE, __HIP_MEMORY_SCOPE_AGENT) < epoch){}
  }
  __syncthreads();
  __threadfence();
}

// ---------------- Kernel 0: input dtype detection (verified) ----------------
__global__ __launch_bounds__(256) void kDetect(const void* __restrict__ x, int* flag){
  __shared__ int cnt;
  if (threadIdx.x == 0) cnt = 0;
  __syncthreads();
  const u16* p = (const u16*)x;
  int bad = 0;
  for (int i = threadIdx.x; i < 1024; i += 256){
    u16 u = p[2*i];
    unsigned e = (u >> 7) & 0xFFu;
    if (e >= 131u) ++bad;
  }
  atomicAdd(&cnt, bad);
  __syncthreads();
  if (threadIdx.x == 0) *flag = (cnt < 102) ? 1 : 0;
}

// ---------------- Kernel B: persistent k-means (R9-verified body) ----------------
template<bool BF>
__device__ void kB_body(const void* __restrict__ x,
                        float* __restrict__ part,
                        float* __restrict__ cnts,
                        int* __restrict__ idxg,
                        void* __restrict__ dout,
                        int* __restrict__ slots,
                        int* __restrict__ gen,
                        const InitIdx& ii){
  const int t   = threadIdx.x;
  const int wg  = blockIdx.x;
  const int mb  = wg >> 4;
  const int sub = wg & 15;
  const int pg  = sub*256 + t;

  __shared__ float obs_st[256][33];
  __shared__ float cent[2][32][32];
  __shared__ float cc_s[32];
  __shared__ int   a_loc[256];
  __shared__ float sq[32][32];
  __shared__ float snorm[32];
  __shared__ float cntsh[32];

  float o[32];
  {
    int h = pg >> 6, w = pg & 63;
    size_t xb = (size_t)mb << 17;
    for (int c=0; c<32; ++c){
      float v = obs_chan<BF>(x, xb + ((size_t)c<<12), h, w);
      o[c] = v; obs_st[t][c] = v;
    }
  }
  if (t < 64){
    int bb = t >> 5, j = t & 31;
    int q = ii.v[bb][j];
    int qh = q >> 6, qw = q & 63;
    size_t xq = (size_t)bb << 17;
    for (int c=0; c<32; ++c) cent[bb][j][c] = obs_chan<BF>(x, xq + ((size_t)c<<12), qh, qw);
  }
  __syncthreads();

  float ss = 0.f;
  #pragma unroll
  for (int d=0; d<32; ++d) ss = fmaf(o[d], o[d], ss);

  bool act0 = true, act1 = true;
  int parity = 0;

  for (int it=0; it<20; ++it){
    if (!(act0 || act1)) break;
    bool mine = (mb==0) ? act0 : act1;
    if (mine){
      if (t < 32){
        float s = 0.f;
        #pragma unroll
        for (int d=0; d<32; ++d){ float v = cent[mb][t][d]; s = fmaf(v,v,s); }
        cc_s[t] = s;
      }
      __syncthreads();
      float best = 3.0e38f; int bk = 0;
      for (int k=0; k<32; ++k){
        const float4* cr4 = (const float4*)&cent[mb][k][0];
        float dot = 0.f;
        #pragma unroll
        for (int d4=0; d4<8; ++d4){
          float4 c4 = cr4[d4];
          dot = fmaf(o[d4*4+0], c4.x, dot);
          dot = fmaf(o[d4*4+1], c4.y, dot);
          dot = fmaf(o[d4*4+2], c4.z, dot);
          dot = fmaf(o[d4*4+3], c4.w, dot);
        }
        float dist = (ss - 2.0f*dot) + cc_s[k];
        if (dist < best){ best = dist; bk = k; }
      }
      a_loc[t] = bk;
      __syncthreads();
      const int d = t & 31, g = t >> 5;
      float s0=0.f, s1=0.f, s2=0.f, s3=0.f;
      #pragma unroll 4
      for (int p=0; p<256; ++p){
        int ap = a_loc[p];
        float v = obs_st[p][d];
        s0 += (ap==g     ) ? v : 0.f;
        s1 += (ap==g + 8 ) ? v : 0.f;
        s2 += (ap==g + 16) ? v : 0.f;
        s3 += (ap==g + 24) ? v : 0.f;
      }
      float* Pg = part + ((size_t)((parity*2 + mb)*SUBS + sub))*1024;
      Pg[(g    )*32 + d] = s0;
      Pg[(g+ 8 )*32 + d] = s1;
      Pg[(g+16 )*32 + d] = s2;
      Pg[(g+24 )*32 + d] = s3;
      if (t < 32){
        int cnt_ = 0;
        #pragma unroll 4
        for (int p=0; p<256; ++p) cnt_ += (a_loc[p] == t) ? 1 : 0;
        cnts[((size_t)((parity*2 + mb)*SUBS + sub))*32 + t] = (float)cnt_;
      }
    }
    gbar2(slots, gen, NWG_KM, it+1);
    for (int bb=0; bb<2; ++bb){
      bool ab = (bb==0) ? act0 : act1;
      if (!ab) continue;
      const float* Pb = part + (size_t)((parity*2 + bb)*SUBS)*1024;
      const float* Cb = cnts + (size_t)((parity*2 + bb)*SUBS)*32;
      if (t < 32){
        float s = 0.f;
        for (int si=0; si<SUBS; ++si) s += Cb[si*32 + t];
        cntsh[t] = s;
      }
      __syncthreads();
      {
        int k = t >> 3, d4 = (t & 7) * 4;
        float4 v = make_float4(0.f, 0.f, 0.f, 0.f);
        for (int si=0; si<SUBS; ++si){
          const float4 p4 = *(const float4*)&Pb[si*1024 + k*32 + d4];
          v.x += p4.x; v.y += p4.y; v.z += p4.z; v.w += p4.w;
        }
        float cn = cntsh[k];
        float den = fmaxf(cn, 1.f);
        bool pos = cn > 0.f;
        float o0 = cent[bb][k][d4+0], o1 = cent[bb][k][d4+1];
        float o2 = cent[bb][k][d4+2], o3 = cent[bb][k][d4+3];
        float n0 = pos ? (v.x / den) : o0;
        float n1 = pos ? (v.y / den) : o1;
        float n2 = pos ? (v.z / den) : o2;
        float n3 = pos ? (v.w / den) : o3;
        float e0 = n0-o0, e1 = n1-o1, e2 = n2-o2, e3 = n3-o3;
        sq[k][d4+0] = e0*e0; sq[k][d4+1] = e1*e1;
        sq[k][d4+2] = e2*e2; sq[k][d4+3] = e3*e3;
        cent[bb][k][d4+0] = n0; cent[bb][k][d4+1] = n1;
        cent[bb][k][d4+2] = n2; cent[bb][k][d4+3] = n3;
      }
      __syncthreads();
      if (t < 32){
        float s = 0.f;
        #pragma unroll
        for (int d=0; d<32; ++d) s += sq[t][d];
        snorm[t] = sqrtf(s);
      }
      __syncthreads();
      float sh = 0.f;
      for (int k=0;k<32;++k) sh += snorm[k];
      bool na = ((it+1) < 20) && ((double)sh >= 20.48);
      if (bb==0) act0 = na; else act1 = na;
      __syncthreads();
    }
    parity ^= 1;
  }
  __syncthreads();
  if (t < 32){
    float s = 0.f;
    #pragma unroll
    for (int d=0; d<32; ++d){ float v = cent[mb][t][d]; s = fmaf(v,v,s); }
    cc_s[t] = s;
  }
  __syncthreads();
  float best = 3.0e38f; int bk = 0;
  for (int k=0; k<32; ++k){
    const float4* cr4 = (const float4*)&cent[mb][k][0];
    float dot = 0.f;
    #pragma unroll
    for (int d4=0; d4<8; ++d4){
      float4 c4 = cr4[d4];
      dot = fmaf(o[d4*4+0], c4.x, dot);
      dot = fmaf(o[d4*4+1], c4.y, dot);
      dot = fmaf(o[d4*4+2], c4.z, dot);
      dot = fmaf(o[d4*4+3], c4.w, dot);
    }
    float dist = (ss - 2.0f*dot) + cc_s[k];
    if (dist < best){ best = dist; bk = k; }
  }
  idxg[mb*PP + pg] = bk;
  st<BF>(dout, (size_t)OUT_ELEMS + mb*PP + pg, (float)bk);
}

__global__ __launch_bounds__(256) void kB(const void* x, float* part, float* cnts,
                                          int* idxg, void* dout,
                                          int* slots, int* gen,
                                          const int* flag, InitIdx ii){
  if (*flag) kB_body<true >(x, part, cnts, idxg, dout, slots, gen, ii);
  else       kB_body<false>(x, part, cnts, idxg, dout, slots, gen, ii);
}

// ---------------- Kernel C v5: wave-per-point cluster patch sums (CHANGE UNDER TEST) -------
// grid 32: wg = (b, chunk of 256 points). Round r: wave wv handles point wv*64+r.
// lane owns 4-5 fixed features (div hoisted); scattered loads pipeline across
// rounds; LDS atomicAdd collisions <=4-way (wave-uniform k). Order-free is OK:
// cpart only feeds centers->MLP (float noise ~1e-6 << 0.62 threshold); idx
// does not depend on cpart.
template<bool BF>
__device__ void kC_body(const void* __restrict__ x,
                        const int* __restrict__ idxg,
                        float* __restrict__ cpart,
                        float* __restrict__ acc,    // [32*292]
                        int* __restrict__ idxsh){   // [256]
  int cg = blockIdx.x;            // 0..31
  int b = cg >> 4, pc = cg & 15;
  int t = threadIdx.x, wv = t >> 6, lane = t & 63;
  for (int e=t; e<32*292; e+=256) acc[e] = 0.f;
  idxsh[t] = idxg[b*PP + pc*256 + t];
  __syncthreads();

  // per-lane feature set: f = lane + 64*i
  const int nf = (lane < 32) ? 5 : 4;
  int fs[5], dh[5], dw[5];
  size_t cb[5];
  size_t xb = (size_t)b << 17;
  #pragma unroll
  for (int i=0; i<5; ++i){
    int f = lane + 64*i;
    if (f >= FF) f = FF-1;           // dummy (only used when i<nf)
    int c = f/9, j = f%9;
    fs[i] = f; dh[i] = j/3 - 1; dw[i] = j%3 - 1;
    cb[i] = xb + ((size_t)c << 12);
  }

  #pragma unroll 2
  for (int r=0; r<64; ++r){
    int p = (wv << 6) + r;           // point within chunk
    int k = idxsh[p];
    int gp = (pc << 8) + p;
    int h = gp >> 6, w = gp & 63;
    float vals[5];
    #pragma unroll
    for (int i=0; i<5; ++i){
      int hh = h + dh[i], ww = w + dw[i];
      float v = 0.f;
      if (i < nf && (unsigned)hh < 64u && (unsigned)ww < 64u)
        v = ld<BF>(x, cb[i] + (hh << 6) + ww);
      vals[i] = v;
    }
    float* ak = &acc[k*292];
    #pragma unroll
    for (int i=0; i<5; ++i){
      if (i < nf) atomicAdd(&ak[fs[i]], vals[i]);
    }
    if (lane == 63) atomicAdd(&ak[288], 1.0f);
  }
  __syncthreads();
  float* cp = cpart + (size_t)cg*(32*289);
  for (int e=t; e<32*289; e+=256)
    cp[e] = acc[(e/289)*292 + (e%289)];
}

__global__ __launch_bounds__(256) void kC(const void* x, const int* idxg,
                                          float* cpart, const int* flag){
  __shared__ float acc[32*292];
  __shared__ int   idxsh[256];
  if (*flag) kC_body<true >(x, idxg, cpart, acc, idxsh);
  else       kC_body<false>(x, idxg, cpart, acc, idxsh);
}

// ---------------- Kernel D: merge partials -> centers + 2 MLPs + softmax (verified) --------
template<bool BF>
__device__ void kD_body(const float* __restrict__ cpart,
                        const void* kg_w1, const void* kg_b1,
                        const void* kg_w2, const void* kg_b2,
                        const void* kg_w3, const void* kg_b3,
                        const void* bg_w1, const void* bg_b1,
                        const void* bg_w2, const void* bg_b2,
                        const void* bg_w3, const void* bg_b3,
                        float* __restrict__ attn,
                        float* __restrict__ biasO,
                        float* __restrict__ row,
                        float* __restrict__ h1,
                        float* __restrict__ h2,
                        float* __restrict__ lgs){
  int wg = blockIdx.x; int b = wg >> 5; int k = wg & 31;
  int t = threadIdx.x;   // 64 threads
  float cnt = 0.f;
  for (int ch=0; ch<16; ++ch)
    cnt += cpart[((size_t)(b*16+ch)*32 + k)*289 + 288];
  float den = fmaxf(cnt, 1.f);
  for (int f=t; f<FF; f+=64){
    float s = 0.f;
    for (int ch=0; ch<16; ++ch)
      s += cpart[((size_t)(b*16+ch)*32 + k)*289 + f];
    row[f] = s / den;
  }
  __syncthreads();

  {
    float s = 0.f;
    #pragma unroll 8
    for (int f=0; f<FF; ++f) s = fmaf(row[f], ld<BF>(kg_w1, f*HID + t), s);
    h1[t] = fmaxf(s + ld<BF>(kg_b1, t), 0.f);
  }
  __syncthreads();
  {
    float s = 0.f;
    #pragma unroll 8
    for (int h=0; h<HID; ++h) s = fmaf(h1[h], ld<BF>(kg_w2, h*HID + t), s);
    h2[t] = fmaxf(s + ld<BF>(kg_b2, t), 0.f);
  }
  __syncthreads();
  if (t < 32){
    float s = 0.f;
    #pragma unroll 8
    for (int h=0; h<HID; ++h) s = fmaf(h2[h], ld<BF>(kg_w3, h*NBASE + t), s);
    lgs[t] = s + ld<BF>(kg_b3, t);
  }
  __syncthreads();
  if (t < 32){
    float mx = -3.0e38f;
    for (int i=0;i<NBASE;++i) mx = fmaxf(mx, lgs[i]);
    float se = 0.f;
    for (int i=0;i<NBASE;++i) se += expf(lgs[i]-mx);
    attn[wg*NBASE + t] = expf(lgs[t]-mx) / se;
  }
  __syncthreads();
  {
    float s = 0.f;
    #pragma unroll 8
    for (int f=0; f<FF; ++f) s = fmaf(row[f], ld<BF>(bg_w1, f*HID + t), s);
    h1[t] = fmaxf(s + ld<BF>(bg_b1, t), 0.f);
  }
  __syncthreads();
  {
    float s = 0.f;
    #pragma unroll 8
    for (int h=0; h<HID; ++h) s = fmaf(h1[h], ld<BF>(bg_w2, h*HID + t), s);
    h2[t] = fmaxf(s + ld<BF>(bg_b2, t), 0.f);
  }
  __syncthreads();
  {
    float s = 0.f;
    #pragma unroll 8
    for (int h=0; h<HID; ++h) s = fmaf(h2[h], ld<BF>(bg_w3, h*COUT + t), s);
    biasO[wg*COUT + t] = s + ld<BF>(bg_b3, t);
  }
}

__global__ __launch_bounds__(64) void kD(const float* cpart,
                                         const void* kg_w1, const void* kg_b1,
                                         const void* kg_w2, const void* kg_b2,
                                         const void* kg_w3, const void* kg_b3,
                                         const void* bg_w1, const void* bg_b1,
                                         const void* bg_w2, const void* bg_b2,
                                         const void* bg_w3, const void* bg_b3,
                                         float* attn, float* biasO, const int* flag){
  __shared__ float row[FF];
  __shared__ float h1[64];
  __shared__ float h2[64];
  __shared__ float lgs[32];
  if (*flag) kD_body<true >(cpart, kg_w1,kg_b1,kg_w2,kg_b2,kg_w3,kg_b3,
                            bg_w1,bg_b1,bg_w2,bg_b2,bg_w3,bg_b3, attn, biasO, row,h1,h2,lgs);
  else       kD_body<false>(cpart, kg_w1,kg_b1,kg_w2,kg_b2,kg_w3,kg_b3,
                            bg_w1,bg_b1,bg_w2,bg_b2,bg_w3,bg_b3, attn, biasO, row,h1,h2,lgs);
}

// ---------------- Kernel E: Wg[b][k][cout][f] (bf16) = sum_n attn*base (verified) ----------
template<bool BF>
__device__ void kE_body(const void* __restrict__ base,
                        const float* __restrict__ attn,
                        u16* __restrict__ Wg,
                        float* __restrict__ at,
                        float* __restrict__ tile){   // [72][65]
  int wg = blockIdx.x;
  int fq = wg & 3, bk = wg >> 2;
  int t = threadIdx.x;
  if (t < 32) at[t] = attn[bk*NBASE + t];
  __syncthreads();
  int f0 = fq*72;
  for (int e=t; e<72*64; e+=256){
    int fl = e >> 6, c = e & 63;
    size_t bi = (size_t)(f0 + fl)*COUT + c;
    float s = 0.f;
    #pragma unroll 8
    for (int n=0; n<NBASE; ++n)
      s = fmaf(at[n], ld<BF>(base, bi + (size_t)n*FF*COUT), s);
    tile[fl*65 + c] = s;
  }
  __syncthreads();
  for (int e=t; e<72*64; e+=256){
    int c = e / 72, fl = e % 72;
    Wg[(size_t)bk*(64*FF) + (size_t)c*FF + f0 + fl] = f2bf(tile[fl*65 + c]);
  }
}

__global__ __launch_bounds__(256) void kE(const void* base, const float* attn,
                                          u16* Wg, const int* flag){
  __shared__ float at[32];
  __shared__ float tile[72*65];
  if (*flag) kE_body<true >(base, attn, Wg, at, tile);
  else       kE_body<false>(base, attn, Wg, at, tile);
}

// ---------------- Kernel F: conv (R5 structure, verified) ----------------
template<bool BF>
__device__ void kF_body(const void* __restrict__ x,
                        const int* __restrict__ idxg,
                        const u16* __restrict__ Wg,
                        const float* __restrict__ biasO,
                        void* __restrict__ dout,
                        u16* __restrict__ patch,    // [16][296]
                        float* __restrict__ outT){  // [64][17]
  int wg = blockIdx.x;
  int q = wg & 3, h = (wg >> 2) & 63, b = wg >> 8;
  int t = threadIdx.x, wv = t >> 6, lane = t & 63;
  int w0 = q << 4;

  for (int e=t; e<16*FF; e+=256){
    int pl = e & 15, fe = e >> 4;
    int c = fe / 9, j = fe % 9;
    int hh = h + j/3 - 1, ww = w0 + pl + (j%3) - 1;
    float v = 0.f;
    if ((unsigned)hh < 64u && (unsigned)ww < 64u)
      v = ld<BF>(x, ((size_t)b << 17) + ((size_t)c << 12) + (hh<<6) + ww);
    patch[pl*296 + fe] = f2bf(v);
  }
  __syncthreads();

  #pragma unroll
  for (int i=0; i<4; ++i){
    int pl = (wv << 2) + i;
    int p = (h << 6) + w0 + pl;
    int k = idxg[(b << 12) + p];
    const uint4* Wp = (const uint4*)(Wg + ((size_t)((b << 5) + k)*64 + lane)*FF);
    const uint4* Pp = (const uint4*)(patch + pl*296);
    float acc = 0.f;
    #pragma unroll 6
    for (int j=0; j<36; ++j){
      uint4 wv4 = Wp[j];
      uint4 pv4 = Pp[j];
      acc = fmaf(u_lo(pv4.x), u_lo(wv4.x), acc);
      acc = fmaf(u_hi(pv4.x), u_hi(wv4.x), acc);
      acc = fmaf(u_lo(pv4.y), u_lo(wv4.y), acc);
      acc = fmaf(u_hi(pv4.y), u_hi(wv4.y), acc);
      acc = fmaf(u_lo(pv4.z), u_lo(wv4.z), acc);
      acc = fmaf(u_hi(pv4.z), u_hi(wv4.z), acc);
      acc = fmaf(u_lo(pv4.w), u_lo(wv4.w), acc);
      acc = fmaf(u_hi(pv4.w), u_hi(wv4.w), acc);
    }
    float bias = biasO[((b << 5) + k)*COUT + lane];
    outT[lane*17 + pl] = acc + bias;
  }
  __syncthreads();

  for (int e=t; e<1024; e+=256){
    int cout = e >> 4, pl = e & 15;
    st<BF>(dout, (((size_t)(b << 6) + cout) << 12) + (h << 6) + w0 + pl,
           outT[cout*17 + pl]);
  }
}

__global__ __launch_bounds__(256) void kF(const void* x, const int* idxg,
                                          const u16* Wg, const float* biasO,
                                          void* dout, const int* flag){
  __shared__ u16   patch[16*296];
  __shared__ float outT[64*17];
  if (*flag) kF_body<true >(x, idxg, Wg, biasO, dout, patch, outT);
  else       kF_body<false>(x, idxg, Wg, biasO, dout, patch, outT);
}

// ---------------- host: JAX threefry2x32 + permutation(key,4096)[:32] ----------------
static inline uint32_t rotl32(uint32_t x, int d){ return (x<<d)|(x>>(32-d)); }
static void tf_block(uint32_t k0,uint32_t k1,uint32_t x0,uint32_t x1,uint32_t&o0,uint32_t&o1){
  uint32_t ks2 = k0 ^ k1 ^ 0x1BD11BDAu;
  uint32_t v0 = x0 + k0, v1 = x1 + k1;
  const int ra[4]={13,15,26,6}, rb[4]={17,29,16,24};
  #define R4(r) for(int i_=0;i_<4;++i_){ v0 += v1; v1 = rotl32(v1,(r)[i_]); v1 ^= v0; }
  R4(ra); v0 += k1;  v1 += ks2 + 1u;
  R4(rb); v0 += ks2; v1 += k0  + 2u;
  R4(ra); v0 += k0;  v1 += k1  + 3u;
  R4(rb); v0 += k1;  v1 += ks2 + 4u;
  R4(ra); v0 += ks2; v1 += k0  + 5u;
  #undef R4
  o0 = v0; o1 = v1;
}
struct KP{ uint32_t a, b; };
static void tf_split(KP k, KP& first, KP& second){
#if THREEFRY_PARTITIONABLE
  uint32_t a0,b0,a1,b1;
  tf_block(k.a,k.b, 0u,0u, a0,b0);
  tf_block(k.a,k.b, 0u,1u, a1,b1);
  first  = KP{a0,b0};
  second = KP{a1,b1};
#else
  uint32_t a0,b0,a1,b1;
  tf_block(k.a,k.b, 0u,2u, a0,b0);
  tf_block(k.a,k.b, 1u,3u, a1,b1);
  first  = KP{a0,a1};
  second = KP{b0,b1};
#endif
}
static void random_bits_4096(KP k, std::vector<uint32_t>& bits){
#if THREEFRY_PARTITIONABLE
  for (int i=0;i<4096;++i){
    uint32_t o0,o1; tf_block(k.a,k.b, 0u,(uint32_t)i, o0,o1);
    bits[i] = o0 ^ o1;
  }
#else
  for (int i=0;i<2048;++i){
    uint32_t o0,o1; tf_block(k.a,k.b,(uint32_t)i,(uint32_t)(i+2048),o0,o1);
    bits[i] = o0; bits[i+2048] = o1;
  }
#endif
}
static void perm_first32(KP key, int* out32){
  std::vector<int> vals(4096);
  for (int i=0;i<4096;++i) vals[i] = i;
  std::vector<uint32_t> bits(4096);
  std::vector<std::pair<uint32_t,int>> pr(4096);
  KP k = key;
  for (int r=0;r<2;++r){
    KP nk, sk; tf_split(k, nk, sk); k = nk;
    random_bits_4096(sk, bits);
    for (int i=0;i<4096;++i) pr[i] = std::make_pair(bits[i], vals[i]);
    std::stable_sort(pr.begin(), pr.end(),
        [](const std::pair<uint32_t,int>& a, const std::pair<uint32_t,int>& c){ return a.first < c.first; });
    for (int i=0;i<4096;++i) vals[i] = pr[i].second;
  }
  for (int j=0;j<32;++j) out32[j] = vals[j];
}

extern "C" void kernel_launch(void* const* d_in, const int* in_sizes, int n_in,
                              void* d_out, int out_size, void* d_ws, size_t ws_size,
                              hipStream_t stream) {
  const void* x     = d_in[0];
  const void* base  = d_in[1];
  const void* kg_w1 = d_in[2];
  const void* kg_b1 = d_in[3];
  const void* kg_w2 = d_in[4];
  const void* kg_b2 = d_in[5];
  const void* kg_w3 = d_in[6];
  const void* kg_b3 = d_in[7];
  const void* bg_w1 = d_in[8];
  const void* bg_b1 = d_in[9];
  const void* bg_w2 = d_in[10];
  const void* bg_b2 = d_in[11];
  const void* bg_w3 = d_in[12];
  const void* bg_b3 = d_in[13];

  char* ws = (char*)d_ws;
  int*   flag  = (int*)(ws + 64);
  int*   idxg  = (int*)(ws + OFF_IDX);
  float* attn  = (float*)(ws + OFF_ATTN);
  float* biasO = (float*)(ws + OFF_BIAS);
  float* part  = (float*)(ws + OFF_PART);
  float* cnts  = (float*)(ws + OFF_CNTS);
  float* cpart = (float*)(ws + OFF_CPART);
  u16*   Wg    = (u16*)(ws + OFF_WG);
  int*   slots = (int*)(ws + OFF_BAR2);
  int*   gen   = (int*)(ws + OFF_BAR2 + 2048);

  InitIdx ii;
  KP root = KP{0u, 42u};
  KP kb0, kb1; tf_split(root, kb0, kb1);
  perm_first32(kb0, ii.v[0]);
  perm_first32(kb1, ii.v[1]);

  hipMemsetAsync(ws + OFF_BAR2, 0, 4096, stream);   // barrier slots + gen

  kDetect<<<1, 256, 0, stream>>>(x, flag);
  kB<<<NWG_KM, 256, 0, stream>>>(x, part, cnts, idxg, d_out, slots, gen, flag, ii);
  kC<<<32, 256, 0, stream>>>(x, idxg, cpart, flag);
  kD<<<64, 64, 0, stream>>>(cpart,
                            kg_w1, kg_b1, kg_w2, kg_b2, kg_w3, kg_b3,
                            bg_w1, bg_b1, bg_w2, bg_b2, bg_w3, bg_b3,
                            attn, biasO, flag);
  kE<<<256, 256, 0, stream>>>(base, attn, Wg, flag);
  kF<<<512, 256, 0, stream>>>(x, idxg, Wg, biasO, d_out, flag);
}

// Round 15
// 374.475 us; speedup vs baseline: 1.1111x; 1.0438x over previous
//
#include <hip/hip_runtime.h>
#include <hip/hip_bf16.h>
#include <vector>
#include <algorithm>
#include <utility>
#include <stdint.h>

// Problem constants
#define BB 2
#define PP 4096        // H*W
#define FF 288         // C*9
#define KK 32
#define NBASE 32
#define HID 64
#define COUT 64
#define NWG_KM 32      // k-means workgroups (16 per batch)
#define SUBS 16
#define OUT_ELEMS 524288   // 2*64*4096; idx chunk follows

#define THREEFRY_PARTITIONABLE 1

typedef unsigned short u16;

// ---------------- ws layout (bytes) ----------------
// [64..67] dtype flag (written by kDetect)
#define OFF_IDX    512          // 2*4096*4  = 32768
#define OFF_ATTN   33280        // 64*32*4   = 8192
#define OFF_BIAS   41472        // 64*64*4   = 16384
#define OFF_PART   57856        // 4 slots * 16 subs * 1024 f32 = 262144 -> 320000
#define OFF_CNTS   320000       // 4 slots * 16 subs * 32 f32   = 8192   -> 328192
#define OFF_CPART  328192       // 32 chunks * 32 k * 289 f32 = 1183744 -> 1511936
#define OFF_WG     1511936      // 64*64*288 u16 (b,k,cout,f) = 2359296 -> 3871232
#define OFF_BAR2   3871232      // slots 32*16 ints (2048) + gen (4); memset 4096

struct InitIdx { int v[2][32]; };

// ---------------- device helpers ----------------
__device__ __forceinline__ float bf2f(u16 u){
  union { unsigned int i; float f; } cv; cv.i = ((unsigned int)u) << 16; return cv.f;
}
__device__ __forceinline__ u16 f2bf(float f){
  union { float f; unsigned int i; } cv; cv.f = f;
  unsigned int x = cv.i;
  unsigned int r = (x + 0x7FFFu + ((x >> 16) & 1u)) >> 16;
  return (u16)r;
}
__device__ __forceinline__ float u_lo(unsigned int u){
  union { unsigned int i; float f; } cv; cv.i = u << 16; return cv.f;
}
__device__ __forceinline__ float u_hi(unsigned int u){
  union { unsigned int i; float f; } cv; cv.i = u & 0xFFFF0000u; return cv.f;
}

template<bool BF>
__device__ __forceinline__ float ld(const void* p, size_t i){
  if constexpr (BF) { return bf2f(((const u16*)p)[i]); }
  else              { return ((const float*)p)[i]; }
}
template<bool BF>
__device__ __forceinline__ void st(void* p, size_t i, float v){
  if constexpr (BF) { ((u16*)p)[i] = f2bf(v); }
  else              { ((float*)p)[i] = v; }
}

template<bool BF>
__device__ __forceinline__ float obs_chan(const void* x, size_t bi, int h, int w){
  float s = 0.f;
  #pragma unroll
  for (int dh=-1; dh<=1; ++dh){
    int hh = h + dh;
    #pragma unroll
    for (int dw=-1; dw<=1; ++dw){
      int ww = w + dw;
      float v = 0.f;
      if ((unsigned)hh < 64u && (unsigned)ww < 64u) v = ld<BF>(x, bi + (hh<<6) + ww);
      s += v;
    }
  }
  return s / 9.0f;
}

// Flag-tree grid barrier (R9-verified)
__device__ __forceinline__ void gbar2(int* slots, int* gen, int nwg, int epoch){
  __syncthreads();
  __threadfence();
  const int t = threadIdx.x;
  const int wg = blockIdx.x;
  if (t == 0)
    __hip_atomic_store(&slots[wg*16], epoch, __ATOMIC_RELEASE, __HIP_MEMORY_SCOPE_AGENT);
  if (wg == 0){
    if (t < nwg){
      while (__hip_atomic_load(&slots[t*16], __ATOMIC_ACQUIRE, __HIP_MEMORY_SCOPE_AGENT) < epoch){}
    }
    __syncthreads();
    if (t == 0)
      __hip_atomic_store(gen, epoch, __ATOMIC_RELEASE, __HIP_MEMORY_SCOPE_AGENT);
  }
  if (t == 0){
    while (__hip_atomic_load(gen, __ATOMIC_ACQUIRE, __HIP_MEMORY_SCOPE_AGENT) < epoch){}
  }
  __syncthreads();
  __threadfence();
}

// ---------------- Kernel 0: input dtype detection (verified) ----------------
__global__ __launch_bounds__(256) void kDetect(const void* __restrict__ x, int* flag){
  __shared__ int cnt;
  if (threadIdx.x == 0) cnt = 0;
  __syncthreads();
  const u16* p = (const u16*)x;
  int bad = 0;
  for (int i = threadIdx.x; i < 1024; i += 256){
    u16 u = p[2*i];
    unsigned e = (u >> 7) & 0xFFu;
    if (e >= 131u) ++bad;
  }
  atomicAdd(&cnt, bad);
  __syncthreads();
  if (threadIdx.x == 0) *flag = (cnt < 102) ? 1 : 0;
}

// ---------------- Kernel B: persistent k-means ----------------
// Changes under test (on R9-verified skeleton, shared hoisted to wrapper):
// (1) octant-exclusive run-accumulated partial sums (acc8[oct][k][d], no atomics,
//     deterministic; reassociation class empirically validated by R12),
// (2) 4-way k-interleaved assignment dots (per-k fma order frozen -> idx bit-identical).
template<bool BF>
__device__ void kB_body(const void* __restrict__ x,
                        float* __restrict__ part,
                        float* __restrict__ cnts,
                        int* __restrict__ idxg,
                        void* __restrict__ dout,
                        int* __restrict__ slots,
                        int* __restrict__ gen,
                        const InitIdx& ii,
                        float* obs_st,   // [256*33]
                        float* cent,     // [2*32*32]
                        float* cc_s,     // [32]
                        int*   a_loc,    // [256]
                        float* sq,       // [32*32]
                        float* snorm,    // [32]
                        float* cntsh,    // [32]
                        float* acc8,     // [8*32*33]
                        float* cnt8){    // [8*32]
  const int t   = threadIdx.x;
  const int wg  = blockIdx.x;
  const int mb  = wg >> 4;
  const int sub = wg & 15;
  const int pg  = sub*256 + t;
  const int d   = t & 31, oct = t >> 5;

  float o[32];
  {
    int h = pg >> 6, w = pg & 63;
    size_t xb = (size_t)mb << 17;
    for (int c=0; c<32; ++c){
      float v = obs_chan<BF>(x, xb + ((size_t)c<<12), h, w);
      o[c] = v; obs_st[t*33 + c] = v;
    }
  }
  if (t < 64){
    int bb = t >> 5, j = t & 31;
    int q = ii.v[bb][j];
    int qh = q >> 6, qw = q & 63;
    size_t xq = (size_t)bb << 17;
    for (int c=0; c<32; ++c) cent[(bb*32 + j)*32 + c] = obs_chan<BF>(x, xq + ((size_t)c<<12), qh, qw);
  }
  __syncthreads();

  float ss = 0.f;
  #pragma unroll
  for (int dd=0; dd<32; ++dd) ss = fmaf(o[dd], o[dd], ss);

  bool act0 = true, act1 = true;
  int parity = 0;

  for (int it=0; it<20; ++it){
    if (!(act0 || act1)) break;
    bool mine = (mb==0) ? act0 : act1;
    if (mine){
      if (t < 32){
        float s = 0.f;
        #pragma unroll
        for (int dd=0; dd<32; ++dd){ float v = cent[(mb*32 + t)*32 + dd]; s = fmaf(v,v,s); }
        cc_s[t] = s;
      }
      __syncthreads();
      // assignment: 4-way k-interleave; per-k dot order o[0..31] frozen
      float best = 3.0e38f; int bk = 0;
      for (int k=0; k<32; k+=4){
        const float4* c0 = (const float4*)&cent[(mb*32 + k  )*32];
        const float4* c1 = (const float4*)&cent[(mb*32 + k+1)*32];
        const float4* c2 = (const float4*)&cent[(mb*32 + k+2)*32];
        const float4* c3 = (const float4*)&cent[(mb*32 + k+3)*32];
        float dt0=0.f, dt1=0.f, dt2=0.f, dt3=0.f;
        #pragma unroll
        for (int q=0; q<8; ++q){
          float4 a0 = c0[q], a1 = c1[q], a2 = c2[q], a3 = c3[q];
          float o0 = o[q*4+0], o1 = o[q*4+1], o2 = o[q*4+2], o3 = o[q*4+3];
          dt0 = fmaf(o0,a0.x,dt0); dt0 = fmaf(o1,a0.y,dt0); dt0 = fmaf(o2,a0.z,dt0); dt0 = fmaf(o3,a0.w,dt0);
          dt1 = fmaf(o0,a1.x,dt1); dt1 = fmaf(o1,a1.y,dt1); dt1 = fmaf(o2,a1.z,dt1); dt1 = fmaf(o3,a1.w,dt1);
          dt2 = fmaf(o0,a2.x,dt2); dt2 = fmaf(o1,a2.y,dt2); dt2 = fmaf(o2,a2.z,dt2); dt2 = fmaf(o3,a2.w,dt2);
          dt3 = fmaf(o0,a3.x,dt3); dt3 = fmaf(o1,a3.y,dt3); dt3 = fmaf(o2,a3.z,dt3); dt3 = fmaf(o3,a3.w,dt3);
        }
        float di0 = (ss - 2.0f*dt0) + cc_s[k];
        float di1 = (ss - 2.0f*dt1) + cc_s[k+1];
        float di2 = (ss - 2.0f*dt2) + cc_s[k+2];
        float di3 = (ss - 2.0f*dt3) + cc_s[k+3];
        if (di0 < best){ best = di0; bk = k; }
        if (di1 < best){ best = di1; bk = k+1; }
        if (di2 < best){ best = di2; bk = k+2; }
        if (di3 < best){ best = di3; bk = k+3; }
      }
      a_loc[t] = bk;
      __syncthreads();
      // octant-exclusive partial sums: thread (oct,d) scans its 32 points,
      // run-accumulates in a register, flushes into exclusively-owned cells.
      for (int e=t; e<8*32*33; e+=256) acc8[e] = 0.f;
      cnt8[t] = 0.f;
      __syncthreads();
      {
        const int p0 = oct*32;
        int kcur = a_loc[p0];
        float racc = 0.f; int rl = 0;
        for (int i=0; i<32; ++i){
          int kp = a_loc[p0+i];
          float v = obs_st[(p0+i)*33 + d];
          if (kp != kcur){
            acc8[(oct*32 + kcur)*33 + d] += racc;
            if (d == 0) cnt8[oct*32 + kcur] += (float)rl;
            racc = 0.f; rl = 0; kcur = kp;
          }
          racc += v; ++rl;
        }
        acc8[(oct*32 + kcur)*33 + d] += racc;
        if (d == 0) cnt8[oct*32 + kcur] += (float)rl;
      }
      __syncthreads();
      // merge octants (fixed order) and write per-wg partials
      float* Pg = part + ((size_t)((parity*2 + mb)*SUBS + sub))*1024;
      {
        float r0=0.f, r1=0.f, r2=0.f, r3=0.f;
        #pragma unroll
        for (int o2=0; o2<8; ++o2){
          r0 += acc8[(o2*32 + oct      )*33 + d];
          r1 += acc8[(o2*32 + oct + 8  )*33 + d];
          r2 += acc8[(o2*32 + oct + 16 )*33 + d];
          r3 += acc8[(o2*32 + oct + 24 )*33 + d];
        }
        Pg[(oct     )*32 + d] = r0;
        Pg[(oct + 8 )*32 + d] = r1;
        Pg[(oct + 16)*32 + d] = r2;
        Pg[(oct + 24)*32 + d] = r3;
      }
      if (t < 32){
        float c = 0.f;
        #pragma unroll
        for (int o2=0; o2<8; ++o2) c += cnt8[o2*32 + t];
        cnts[((size_t)((parity*2 + mb)*SUBS + sub))*32 + t] = c;
      }
    }
    gbar2(slots, gen, NWG_KM, it+1);
    for (int bb=0; bb<2; ++bb){
      bool ab = (bb==0) ? act0 : act1;
      if (!ab) continue;
      const float* Pb = part + (size_t)((parity*2 + bb)*SUBS)*1024;
      const float* Cb = cnts + (size_t)((parity*2 + bb)*SUBS)*32;
      if (t < 32){
        float s = 0.f;
        for (int si=0; si<SUBS; ++si) s += Cb[si*32 + t];
        cntsh[t] = s;
      }
      __syncthreads();
      {
        int k = t >> 3, d4 = (t & 7) * 4;
        float4 v = make_float4(0.f, 0.f, 0.f, 0.f);
        for (int si=0; si<SUBS; ++si){
          const float4 p4 = *(const float4*)&Pb[si*1024 + k*32 + d4];
          v.x += p4.x; v.y += p4.y; v.z += p4.z; v.w += p4.w;
        }
        float cn = cntsh[k];
        float den = fmaxf(cn, 1.f);
        bool pos = cn > 0.f;
        float o0 = cent[(bb*32 + k)*32 + d4+0], o1 = cent[(bb*32 + k)*32 + d4+1];
        float o2 = cent[(bb*32 + k)*32 + d4+2], o3 = cent[(bb*32 + k)*32 + d4+3];
        float n0 = pos ? (v.x / den) : o0;
        float n1 = pos ? (v.y / den) : o1;
        float n2 = pos ? (v.z / den) : o2;
        float n3 = pos ? (v.w / den) : o3;
        float e0 = n0-o0, e1 = n1-o1, e2 = n2-o2, e3 = n3-o3;
        sq[k*32 + d4+0] = e0*e0; sq[k*32 + d4+1] = e1*e1;
        sq[k*32 + d4+2] = e2*e2; sq[k*32 + d4+3] = e3*e3;
        cent[(bb*32 + k)*32 + d4+0] = n0; cent[(bb*32 + k)*32 + d4+1] = n1;
        cent[(bb*32 + k)*32 + d4+2] = n2; cent[(bb*32 + k)*32 + d4+3] = n3;
      }
      __syncthreads();
      if (t < 32){
        float s = 0.f;
        #pragma unroll
        for (int dd=0; dd<32; ++dd) s += sq[t*32 + dd];
        snorm[t] = sqrtf(s);
      }
      __syncthreads();
      float sh = 0.f;
      for (int k=0;k<32;++k) sh += snorm[k];
      bool na = ((it+1) < 20) && ((double)sh >= 20.48);
      if (bb==0) act0 = na; else act1 = na;
      __syncthreads();
    }
    parity ^= 1;
  }
  __syncthreads();
  if (t < 32){
    float s = 0.f;
    #pragma unroll
    for (int dd=0; dd<32; ++dd){ float v = cent[(mb*32 + t)*32 + dd]; s = fmaf(v,v,s); }
    cc_s[t] = s;
  }
  __syncthreads();
  float best = 3.0e38f; int bk = 0;
  for (int k=0; k<32; k+=4){
    const float4* c0 = (const float4*)&cent[(mb*32 + k  )*32];
    const float4* c1 = (const float4*)&cent[(mb*32 + k+1)*32];
    const float4* c2 = (const float4*)&cent[(mb*32 + k+2)*32];
    const float4* c3 = (const float4*)&cent[(mb*32 + k+3)*32];
    float dt0=0.f, dt1=0.f, dt2=0.f, dt3=0.f;
    #pragma unroll
    for (int q=0; q<8; ++q){
      float4 a0 = c0[q], a1 = c1[q], a2 = c2[q], a3 = c3[q];
      float o0 = o[q*4+0], o1 = o[q*4+1], o2 = o[q*4+2], o3 = o[q*4+3];
      dt0 = fmaf(o0,a0.x,dt0); dt0 = fmaf(o1,a0.y,dt0); dt0 = fmaf(o2,a0.z,dt0); dt0 = fmaf(o3,a0.w,dt0);
      dt1 = fmaf(o0,a1.x,dt1); dt1 = fmaf(o1,a1.y,dt1); dt1 = fmaf(o2,a1.z,dt1); dt1 = fmaf(o3,a1.w,dt1);
      dt2 = fmaf(o0,a2.x,dt2); dt2 = fmaf(o1,a2.y,dt2); dt2 = fmaf(o2,a2.z,dt2); dt2 = fmaf(o3,a2.w,dt2);
      dt3 = fmaf(o0,a3.x,dt3); dt3 = fmaf(o1,a3.y,dt3); dt3 = fmaf(o2,a3.z,dt3); dt3 = fmaf(o3,a3.w,dt3);
    }
    float di0 = (ss - 2.0f*dt0) + cc_s[k];
    float di1 = (ss - 2.0f*dt1) + cc_s[k+1];
    float di2 = (ss - 2.0f*dt2) + cc_s[k+2];
    float di3 = (ss - 2.0f*dt3) + cc_s[k+3];
    if (di0 < best){ best = di0; bk = k; }
    if (di1 < best){ best = di1; bk = k+1; }
    if (di2 < best){ best = di2; bk = k+2; }
    if (di3 < best){ best = di3; bk = k+3; }
  }
  idxg[mb*PP + pg] = bk;
  st<BF>(dout, (size_t)OUT_ELEMS + mb*PP + pg, (float)bk);
}

__global__ __launch_bounds__(256) void kB(const void* x, float* part, float* cnts,
                                          int* idxg, void* dout,
                                          int* slots, int* gen,
                                          const int* flag, InitIdx ii){
  __shared__ __align__(16) float obs_st[256*33];
  __shared__ __align__(16) float cent[2*32*32];
  __shared__ float cc_s[32];
  __shared__ int   a_loc[256];
  __shared__ float sq[32*32];
  __shared__ float snorm[32];
  __shared__ float cntsh[32];
  __shared__ float acc8[8*32*33];
  __shared__ float cnt8[8*32];
  if (*flag) kB_body<true >(x, part, cnts, idxg, dout, slots, gen, ii,
                            obs_st, cent, cc_s, a_loc, sq, snorm, cntsh, acc8, cnt8);
  else       kB_body<false>(x, part, cnts, idxg, dout, slots, gen, ii,
                            obs_st, cent, cc_s, a_loc, sq, snorm, cntsh, acc8, cnt8);
}

// ---------------- Kernel C v5: wave-per-point cluster patch sums (R14-verified) ------------
template<bool BF>
__device__ void kC_body(const void* __restrict__ x,
                        const int* __restrict__ idxg,
                        float* __restrict__ cpart,
                        float* __restrict__ acc,    // [32*292]
                        int* __restrict__ idxsh){   // [256]
  int cg = blockIdx.x;            // 0..31
  int b = cg >> 4, pc = cg & 15;
  int t = threadIdx.x, wv = t >> 6, lane = t & 63;
  for (int e=t; e<32*292; e+=256) acc[e] = 0.f;
  idxsh[t] = idxg[b*PP + pc*256 + t];
  __syncthreads();

  const int nf = (lane < 32) ? 5 : 4;
  int fs[5], dh[5], dw[5];
  size_t cb[5];
  size_t xb = (size_t)b << 17;
  #pragma unroll
  for (int i=0; i<5; ++i){
    int f = lane + 64*i;
    if (f >= FF) f = FF-1;
    int c = f/9, j = f%9;
    fs[i] = f; dh[i] = j/3 - 1; dw[i] = j%3 - 1;
    cb[i] = xb + ((size_t)c << 12);
  }

  #pragma unroll 2
  for (int r=0; r<64; ++r){
    int p = (wv << 6) + r;
    int k = idxsh[p];
    int gp = (pc << 8) + p;
    int h = gp >> 6, w = gp & 63;
    float vals[5];
    #pragma unroll
    for (int i=0; i<5; ++i){
      int hh = h + dh[i], ww = w + dw[i];
      float v = 0.f;
      if (i < nf && (unsigned)hh < 64u && (unsigned)ww < 64u)
        v = ld<BF>(x, cb[i] + (hh << 6) + ww);
      vals[i] = v;
    }
    float* ak = &acc[k*292];
    #pragma unroll
    for (int i=0; i<5; ++i){
      if (i < nf) atomicAdd(&ak[fs[i]], vals[i]);
    }
    if (lane == 63) atomicAdd(&ak[288], 1.0f);
  }
  __syncthreads();
  float* cp = cpart + (size_t)cg*(32*289);
  for (int e=t; e<32*289; e+=256)
    cp[e] = acc[(e/289)*292 + (e%289)];
}

__global__ __launch_bounds__(256) void kC(const void* x, const int* idxg,
                                          float* cpart, const int* flag){
  __shared__ float acc[32*292];
  __shared__ int   idxsh[256];
  if (*flag) kC_body<true >(x, idxg, cpart, acc, idxsh);
  else       kC_body<false>(x, idxg, cpart, acc, idxsh);
}

// ---------------- Kernel D: merge partials -> centers + 2 MLPs + softmax (verified) --------
template<bool BF>
__device__ void kD_body(const float* __restrict__ cpart,
                        const void* kg_w1, const void* kg_b1,
                        const void* kg_w2, const void* kg_b2,
                        const void* kg_w3, const void* kg_b3,
                        const void* bg_w1, const void* bg_b1,
                        const void* bg_w2, const void* bg_b2,
                        const void* bg_w3, const void* bg_b3,
                        float* __restrict__ attn,
                        float* __restrict__ biasO,
                        float* __restrict__ row,
                        float* __restrict__ h1,
                        float* __restrict__ h2,
                        float* __restrict__ lgs){
  int wg = blockIdx.x; int b = wg >> 5; int k = wg & 31;
  int t = threadIdx.x;   // 64 threads
  float cnt = 0.f;
  for (int ch=0; ch<16; ++ch)
    cnt += cpart[((size_t)(b*16+ch)*32 + k)*289 + 288];
  float den = fmaxf(cnt, 1.f);
  for (int f=t; f<FF; f+=64){
    float s = 0.f;
    for (int ch=0; ch<16; ++ch)
      s += cpart[((size_t)(b*16+ch)*32 + k)*289 + f];
    row[f] = s / den;
  }
  __syncthreads();

  {
    float s = 0.f;
    #pragma unroll 8
    for (int f=0; f<FF; ++f) s = fmaf(row[f], ld<BF>(kg_w1, f*HID + t), s);
    h1[t] = fmaxf(s + ld<BF>(kg_b1, t), 0.f);
  }
  __syncthreads();
  {
    float s = 0.f;
    #pragma unroll 8
    for (int h=0; h<HID; ++h) s = fmaf(h1[h], ld<BF>(kg_w2, h*HID + t), s);
    h2[t] = fmaxf(s + ld<BF>(kg_b2, t), 0.f);
  }
  __syncthreads();
  if (t < 32){
    float s = 0.f;
    #pragma unroll 8
    for (int h=0; h<HID; ++h) s = fmaf(h2[h], ld<BF>(kg_w3, h*NBASE + t), s);
    lgs[t] = s + ld<BF>(kg_b3, t);
  }
  __syncthreads();
  if (t < 32){
    float mx = -3.0e38f;
    for (int i=0;i<NBASE;++i) mx = fmaxf(mx, lgs[i]);
    float se = 0.f;
    for (int i=0;i<NBASE;++i) se += expf(lgs[i]-mx);
    attn[wg*NBASE + t] = expf(lgs[t]-mx) / se;
  }
  __syncthreads();
  {
    float s = 0.f;
    #pragma unroll 8
    for (int f=0; f<FF; ++f) s = fmaf(row[f], ld<BF>(bg_w1, f*HID + t), s);
    h1[t] = fmaxf(s + ld<BF>(bg_b1, t), 0.f);
  }
  __syncthreads();
  {
    float s = 0.f;
    #pragma unroll 8
    for (int h=0; h<HID; ++h) s = fmaf(h1[h], ld<BF>(bg_w2, h*HID + t), s);
    h2[t] = fmaxf(s + ld<BF>(bg_b2, t), 0.f);
  }
  __syncthreads();
  {
    float s = 0.f;
    #pragma unroll 8
    for (int h=0; h<HID; ++h) s = fmaf(h2[h], ld<BF>(bg_w3, h*COUT + t), s);
    biasO[wg*COUT + t] = s + ld<BF>(bg_b3, t);
  }
}

__global__ __launch_bounds__(64) void kD(const float* cpart,
                                         const void* kg_w1, const void* kg_b1,
                                         const void* kg_w2, const void* kg_b2,
                                         const void* kg_w3, const void* kg_b3,
                                         const void* bg_w1, const void* bg_b1,
                                         const void* bg_w2, const void* bg_b2,
                                         const void* bg_w3, const void* bg_b3,
                                         float* attn, float* biasO, const int* flag){
  __shared__ float row[FF];
  __shared__ float h1[64];
  __shared__ float h2[64];
  __shared__ float lgs[32];
  if (*flag) kD_body<true >(cpart, kg_w1,kg_b1,kg_w2,kg_b2,kg_w3,kg_b3,
                            bg_w1,bg_b1,bg_w2,bg_b2,bg_w3,bg_b3, attn, biasO, row,h1,h2,lgs);
  else       kD_body<false>(cpart, kg_w1,kg_b1,kg_w2,kg_b2,kg_w3,kg_b3,
                            bg_w1,bg_b1,bg_w2,bg_b2,bg_w3,bg_b3, attn, biasO, row,h1,h2,lgs);
}

// ---------------- Kernel E: Wg[b][k][cout][f] (bf16) = sum_n attn*base (verified) ----------
template<bool BF>
__device__ void kE_body(const void* __restrict__ base,
                        const float* __restrict__ attn,
                        u16* __restrict__ Wg,
                        float* __restrict__ at,
                        float* __restrict__ tile){   // [72][65]
  int wg = blockIdx.x;
  int fq = wg & 3, bk = wg >> 2;
  int t = threadIdx.x;
  if (t < 32) at[t] = attn[bk*NBASE + t];
  __syncthreads();
  int f0 = fq*72;
  for (int e=t; e<72*64; e+=256){
    int fl = e >> 6, c = e & 63;
    size_t bi = (size_t)(f0 + fl)*COUT + c;
    float s = 0.f;
    #pragma unroll 8
    for (int n=0; n<NBASE; ++n)
      s = fmaf(at[n], ld<BF>(base, bi + (size_t)n*FF*COUT), s);
    tile[fl*65 + c] = s;
  }
  __syncthreads();
  for (int e=t; e<72*64; e+=256){
    int c = e / 72, fl = e % 72;
    Wg[(size_t)bk*(64*FF) + (size_t)c*FF + f0 + fl] = f2bf(tile[fl*65 + c]);
  }
}

__global__ __launch_bounds__(256) void kE(const void* base, const float* attn,
                                          u16* Wg, const int* flag){
  __shared__ float at[32];
  __shared__ float tile[72*65];
  if (*flag) kE_body<true >(base, attn, Wg, at, tile);
  else       kE_body<false>(base, attn, Wg, at, tile);
}

// ---------------- Kernel F: conv (R5 structure, verified) ----------------
template<bool BF>
__device__ void kF_body(const void* __restrict__ x,
                        const int* __restrict__ idxg,
                        const u16* __restrict__ Wg,
                        const float* __restrict__ biasO,
                        void* __restrict__ dout,
                        u16* __restrict__ patch,    // [16][296]
                        float* __restrict__ outT){  // [64][17]
  int wg = blockIdx.x;
  int q = wg & 3, h = (wg >> 2) & 63, b = wg >> 8;
  int t = threadIdx.x, wv = t >> 6, lane = t & 63;
  int w0 = q << 4;

  for (int e=t; e<16*FF; e+=256){
    int pl = e & 15, fe = e >> 4;
    int c = fe / 9, j = fe % 9;
    int hh = h + j/3 - 1, ww = w0 + pl + (j%3) - 1;
    float v = 0.f;
    if ((unsigned)hh < 64u && (unsigned)ww < 64u)
      v = ld<BF>(x, ((size_t)b << 17) + ((size_t)c << 12) + (hh<<6) + ww);
    patch[pl*296 + fe] = f2bf(v);
  }
  __syncthreads();

  #pragma unroll
  for (int i=0; i<4; ++i){
    int pl = (wv << 2) + i;
    int p = (h << 6) + w0 + pl;
    int k = idxg[(b << 12) + p];
    const uint4* Wp = (const uint4*)(Wg + ((size_t)((b << 5) + k)*64 + lane)*FF);
    const uint4* Pp = (const uint4*)(patch + pl*296);
    float acc = 0.f;
    #pragma unroll 6
    for (int j=0; j<36; ++j){
      uint4 wv4 = Wp[j];
      uint4 pv4 = Pp[j];
      acc = fmaf(u_lo(pv4.x), u_lo(wv4.x), acc);
      acc = fmaf(u_hi(pv4.x), u_hi(wv4.x), acc);
      acc = fmaf(u_lo(pv4.y), u_lo(wv4.y), acc);
      acc = fmaf(u_hi(pv4.y), u_hi(wv4.y), acc);
      acc = fmaf(u_lo(pv4.z), u_lo(wv4.z), acc);
      acc = fmaf(u_hi(pv4.z), u_hi(wv4.z), acc);
      acc = fmaf(u_lo(pv4.w), u_lo(wv4.w), acc);
      acc = fmaf(u_hi(pv4.w), u_hi(wv4.w), acc);
    }
    float bias = biasO[((b << 5) + k)*COUT + lane];
    outT[lane*17 + pl] = acc + bias;
  }
  __syncthreads();

  for (int e=t; e<1024; e+=256){
    int cout = e >> 4, pl = e & 15;
    st<BF>(dout, (((size_t)(b << 6) + cout) << 12) + (h << 6) + w0 + pl,
           outT[cout*17 + pl]);
  }
}

__global__ __launch_bounds__(256) void kF(const void* x, const int* idxg,
                                          const u16* Wg, const float* biasO,
                                          void* dout, const int* flag){
  __shared__ u16   patch[16*296];
  __shared__ float outT[64*17];
  if (*flag) kF_body<true >(x, idxg, Wg, biasO, dout, patch, outT);
  else       kF_body<false>(x, idxg, Wg, biasO, dout, patch, outT);
}

// ---------------- host: JAX threefry2x32 + permutation(key,4096)[:32] ----------------
static inline uint32_t rotl32(uint32_t x, int d){ return (x<<d)|(x>>(32-d)); }
static void tf_block(uint32_t k0,uint32_t k1,uint32_t x0,uint32_t x1,uint32_t&o0,uint32_t&o1){
  uint32_t ks2 = k0 ^ k1 ^ 0x1BD11BDAu;
  uint32_t v0 = x0 + k0, v1 = x1 + k1;
  const int ra[4]={13,15,26,6}, rb[4]={17,29,16,24};
  #define R4(r) for(int i_=0;i_<4;++i_){ v0 += v1; v1 = rotl32(v1,(r)[i_]); v1 ^= v0; }
  R4(ra); v0 += k1;  v1 += ks2 + 1u;
  R4(rb); v0 += ks2; v1 += k0  + 2u;
  R4(ra); v0 += k0;  v1 += k1  + 3u;
  R4(rb); v0 += k1;  v1 += ks2 + 4u;
  R4(ra); v0 += ks2; v1 += k0  + 5u;
  #undef R4
  o0 = v0; o1 = v1;
}
struct KP{ uint32_t a, b; };
static void tf_split(KP k, KP& first, KP& second){
#if THREEFRY_PARTITIONABLE
  uint32_t a0,b0,a1,b1;
  tf_block(k.a,k.b, 0u,0u, a0,b0);
  tf_block(k.a,k.b, 0u,1u, a1,b1);
  first  = KP{a0,b0};
  second = KP{a1,b1};
#else
  uint32_t a0,b0,a1,b1;
  tf_block(k.a,k.b, 0u,2u, a0,b0);
  tf_block(k.a,k.b, 1u,3u, a1,b1);
  first  = KP{a0,a1};
  second = KP{b0,b1};
#endif
}
static void random_bits_4096(KP k, std::vector<uint32_t>& bits){
#if THREEFRY_PARTITIONABLE
  for (int i=0;i<4096;++i){
    uint32_t o0,o1; tf_block(k.a,k.b, 0u,(uint32_t)i, o0,o1);
    bits[i] = o0 ^ o1;
  }
#else
  for (int i=0;i<2048;++i){
    uint32_t o0,o1; tf_block(k.a,k.b,(uint32_t)i,(uint32_t)(i+2048),o0,o1);
    bits[i] = o0; bits[i+2048] = o1;
  }
#endif
}
static void perm_first32(KP key, int* out32){
  std::vector<int> vals(4096);
  for (int i=0;i<4096;++i) vals[i] = i;
  std::vector<uint32_t> bits(4096);
  std::vector<std::pair<uint32_t,int>> pr(4096);
  KP k = key;
  for (int r=0;r<2;++r){
    KP nk, sk; tf_split(k, nk, sk); k = nk;
    random_bits_4096(sk, bits);
    for (int i=0;i<4096;++i) pr[i] = std::make_pair(bits[i], vals[i]);
    std::stable_sort(pr.begin(), pr.end(),
        [](const std::pair<uint32_t,int>& a, const std::pair<uint32_t,int>& c){ return a.first < c.first; });
    for (int i=0;i<4096;++i) vals[i] = pr[i].second;
  }
  for (int j=0;j<32;++j) out32[j] = vals[j];
}

extern "C" void kernel_launch(void* const* d_in, const int* in_sizes, int n_in,
                              void* d_out, int out_size, void* d_ws, size_t ws_size,
                              hipStream_t stream) {
  const void* x     = d_in[0];
  const void* base  = d_in[1];
  const void* kg_w1 = d_in[2];
  const void* kg_b1 = d_in[3];
  const void* kg_w2 = d_in[4];
  const void* kg_b2 = d_in[5];
  const void* kg_w3 = d_in[6];
  const void* kg_b3 = d_in[7];
  const void* bg_w1 = d_in[8];
  const void* bg_b1 = d_in[9];
  const void* bg_w2 = d_in[10];
  const void* bg_b2 = d_in[11];
  const void* bg_w3 = d_in[12];
  const void* bg_b3 = d_in[13];

  char* ws = (char*)d_ws;
  int*   flag  = (int*)(ws + 64);
  int*   idxg  = (int*)(ws + OFF_IDX);
  float* attn  = (float*)(ws + OFF_ATTN);
  float* biasO = (float*)(ws + OFF_BIAS);
  float* part  = (float*)(ws + OFF_PART);
  float* cnts  = (float*)(ws + OFF_CNTS);
  float* cpart = (float*)(ws + OFF_CPART);
  u16*   Wg    = (u16*)(ws + OFF_WG);
  int*   slots = (int*)(ws + OFF_BAR2);
  int*   gen   = (int*)(ws + OFF_BAR2 + 2048);

  InitIdx ii;
  KP root = KP{0u, 42u};
  KP kb0, kb1; tf_split(root, kb0, kb1);
  perm_first32(kb0, ii.v[0]);
  perm_first32(kb1, ii.v[1]);

  hipMemsetAsync(ws + OFF_BAR2, 0, 4096, stream);   // barrier slots + gen

  kDetect<<<1, 256, 0, stream>>>(x, flag);
  kB<<<NWG_KM, 256, 0, stream>>>(x, part, cnts, idxg, d_out, slots, gen, flag, ii);
  kC<<<32, 256, 0, stream>>>(x, idxg, cpart, flag);
  kD<<<64, 64, 0, stream>>>(cpart,
                            kg_w1, kg_b1, kg_w2, kg_b2, kg_w3, kg_b3,
                            bg_w1, bg_b1, bg_w2, bg_b2, bg_w3, bg_b3,
                            attn, biasO, flag);
  kE<<<256, 256, 0, stream>>>(base, attn, Wg, flag);
  kF<<<512, 256, 0, stream>>>(x, idxg, Wg, biasO, d_out, flag);
}

// Round 16
// 299.175 us; speedup vs baseline: 1.3908x; 1.2517x over previous
//
#include <hip/hip_runtime.h>
#include <hip/hip_bf16.h>
#include <vector>
#include <algorithm>
#include <utility>
#include <stdint.h>

// Problem constants
#define BB 2
#define PP 4096        // H*W
#define FF 288         // C*9
#define KK 32
#define NBASE 32
#define HID 64
#define COUT 64
#define NWG_KM 32      // k-means workgroups (16 per batch)
#define SUBS 16
#define OUT_ELEMS 524288   // 2*64*4096; idx chunk follows

#define THREEFRY_PARTITIONABLE 1

typedef unsigned short u16;

// ---------------- ws layout (bytes) ----------------
// [64..67] dtype flag (written by kDetect)
#define OFF_IDX    512          // 2*4096*4  = 32768
#define OFF_ATTN   33280        // 64*32*4   = 8192
#define OFF_BIAS   41472        // 64*64*4   = 16384
#define OFF_PART   57856        // 4 slots * 16 subs * 1024 f32 = 262144 -> 320000
#define OFF_CNTS   320000       // 4 slots * 16 subs * 32 f32   = 8192   -> 328192
#define OFF_CPART  328192       // 288 wgs * 32 k * 33 f32 = 1216512 -> 1544704
#define OFF_WG     1544704      // 64*64*288 u16 (b,k,cout,f) = 2359296 -> 3904000
#define OFF_BAR2   3904000      // slots 32*16 ints (2048) + gen (4); memset 4096

struct InitIdx { int v[2][32]; };

// ---------------- device helpers ----------------
__device__ __forceinline__ float bf2f(u16 u){
  union { unsigned int i; float f; } cv; cv.i = ((unsigned int)u) << 16; return cv.f;
}
__device__ __forceinline__ u16 f2bf(float f){
  union { float f; unsigned int i; } cv; cv.f = f;
  unsigned int x = cv.i;
  unsigned int r = (x + 0x7FFFu + ((x >> 16) & 1u)) >> 16;
  return (u16)r;
}
__device__ __forceinline__ float u_lo(unsigned int u){
  union { unsigned int i; float f; } cv; cv.i = u << 16; return cv.f;
}
__device__ __forceinline__ float u_hi(unsigned int u){
  union { unsigned int i; float f; } cv; cv.i = u & 0xFFFF0000u; return cv.f;
}

template<bool BF>
__device__ __forceinline__ float ld(const void* p, size_t i){
  if constexpr (BF) { return bf2f(((const u16*)p)[i]); }
  else              { return ((const float*)p)[i]; }
}
template<bool BF>
__device__ __forceinline__ void st(void* p, size_t i, float v){
  if constexpr (BF) { ((u16*)p)[i] = f2bf(v); }
  else              { ((float*)p)[i] = v; }
}

template<bool BF>
__device__ __forceinline__ float obs_chan(const void* x, size_t bi, int h, int w){
  float s = 0.f;
  #pragma unroll
  for (int dh=-1; dh<=1; ++dh){
    int hh = h + dh;
    #pragma unroll
    for (int dw=-1; dw<=1; ++dw){
      int ww = w + dw;
      float v = 0.f;
      if ((unsigned)hh < 64u && (unsigned)ww < 64u) v = ld<BF>(x, bi + (hh<<6) + ww);
      s += v;
    }
  }
  return s / 9.0f;
}

// Flag-tree grid barrier (R9-verified)
__device__ __forceinline__ void gbar2(int* slots, int* gen, int nwg, int epoch){
  __syncthreads();
  __threadfence();
  const int t = threadIdx.x;
  const int wg = blockIdx.x;
  if (t == 0)
    __hip_atomic_store(&slots[wg*16], epoch, __ATOMIC_RELEASE, __HIP_MEMORY_SCOPE_AGENT);
  if (wg == 0){
    if (t < nwg){
      while (__hip_atomic_load(&slots[t*16], __ATOMIC_ACQUIRE, __HIP_MEMORY_SCOPE_AGENT) < epoch){}
    }
    __syncthreads();
    if (t == 0)
      __hip_atomic_store(gen, epoch, __ATOMIC_RELEASE, __HIP_MEMORY_SCOPE_AGENT);
  }
  if (t == 0){
    while (__hip_atomic_load(gen, __ATOMIC_ACQUIRE, __HIP_MEMORY_SCOPE_AGENT) < epoch){}
  }
  __syncthreads();
  __threadfence();
}

// ---------------- Kernel 0: input dtype detection (verified) ----------------
__global__ __launch_bounds__(256) void kDetect(const void* __restrict__ x, int* flag){
  __shared__ int cnt;
  if (threadIdx.x == 0) cnt = 0;
  __syncthreads();
  const u16* p = (const u16*)x;
  int bad = 0;
  for (int i = threadIdx.x; i < 1024; i += 256){
    u16 u = p[2*i];
    unsigned e = (u >> 7) & 0xFFu;
    if (e >= 131u) ++bad;
  }
  atomicAdd(&cnt, bad);
  __syncthreads();
  if (threadIdx.x == 0) *flag = (cnt < 102) ? 1 : 0;
}

// ---------------- Kernel B: persistent k-means (R15-verified body) ----------------
template<bool BF>
__device__ void kB_body(const void* __restrict__ x,
                        float* __restrict__ part,
                        float* __restrict__ cnts,
                        int* __restrict__ idxg,
                        void* __restrict__ dout,
                        int* __restrict__ slots,
                        int* __restrict__ gen,
                        const InitIdx& ii,
                        float* obs_st,   // [256*33]
                        float* cent,     // [2*32*32]
                        float* cc_s,     // [32]
                        int*   a_loc,    // [256]
                        float* sq,       // [32*32]
                        float* snorm,    // [32]
                        float* cntsh,    // [32]
                        float* acc8,     // [8*32*33]
                        float* cnt8){    // [8*32]
  const int t   = threadIdx.x;
  const int wg  = blockIdx.x;
  const int mb  = wg >> 4;
  const int sub = wg & 15;
  const int pg  = sub*256 + t;
  const int d   = t & 31, oct = t >> 5;

  float o[32];
  {
    int h = pg >> 6, w = pg & 63;
    size_t xb = (size_t)mb << 17;
    for (int c=0; c<32; ++c){
      float v = obs_chan<BF>(x, xb + ((size_t)c<<12), h, w);
      o[c] = v; obs_st[t*33 + c] = v;
    }
  }
  if (t < 64){
    int bb = t >> 5, j = t & 31;
    int q = ii.v[bb][j];
    int qh = q >> 6, qw = q & 63;
    size_t xq = (size_t)bb << 17;
    for (int c=0; c<32; ++c) cent[(bb*32 + j)*32 + c] = obs_chan<BF>(x, xq + ((size_t)c<<12), qh, qw);
  }
  __syncthreads();

  float ss = 0.f;
  #pragma unroll
  for (int dd=0; dd<32; ++dd) ss = fmaf(o[dd], o[dd], ss);

  bool act0 = true, act1 = true;
  int parity = 0;

  for (int it=0; it<20; ++it){
    if (!(act0 || act1)) break;
    bool mine = (mb==0) ? act0 : act1;
    if (mine){
      if (t < 32){
        float s = 0.f;
        #pragma unroll
        for (int dd=0; dd<32; ++dd){ float v = cent[(mb*32 + t)*32 + dd]; s = fmaf(v,v,s); }
        cc_s[t] = s;
      }
      __syncthreads();
      float best = 3.0e38f; int bk = 0;
      for (int k=0; k<32; k+=4){
        const float4* c0 = (const float4*)&cent[(mb*32 + k  )*32];
        const float4* c1 = (const float4*)&cent[(mb*32 + k+1)*32];
        const float4* c2 = (const float4*)&cent[(mb*32 + k+2)*32];
        const float4* c3 = (const float4*)&cent[(mb*32 + k+3)*32];
        float dt0=0.f, dt1=0.f, dt2=0.f, dt3=0.f;
        #pragma unroll
        for (int q=0; q<8; ++q){
          float4 a0 = c0[q], a1 = c1[q], a2 = c2[q], a3 = c3[q];
          float o0 = o[q*4+0], o1 = o[q*4+1], o2 = o[q*4+2], o3 = o[q*4+3];
          dt0 = fmaf(o0,a0.x,dt0); dt0 = fmaf(o1,a0.y,dt0); dt0 = fmaf(o2,a0.z,dt0); dt0 = fmaf(o3,a0.w,dt0);
          dt1 = fmaf(o0,a1.x,dt1); dt1 = fmaf(o1,a1.y,dt1); dt1 = fmaf(o2,a1.z,dt1); dt1 = fmaf(o3,a1.w,dt1);
          dt2 = fmaf(o0,a2.x,dt2); dt2 = fmaf(o1,a2.y,dt2); dt2 = fmaf(o2,a2.z,dt2); dt2 = fmaf(o3,a2.w,dt2);
          dt3 = fmaf(o0,a3.x,dt3); dt3 = fmaf(o1,a3.y,dt3); dt3 = fmaf(o2,a3.z,dt3); dt3 = fmaf(o3,a3.w,dt3);
        }
        float di0 = (ss - 2.0f*dt0) + cc_s[k];
        float di1 = (ss - 2.0f*dt1) + cc_s[k+1];
        float di2 = (ss - 2.0f*dt2) + cc_s[k+2];
        float di3 = (ss - 2.0f*dt3) + cc_s[k+3];
        if (di0 < best){ best = di0; bk = k; }
        if (di1 < best){ best = di1; bk = k+1; }
        if (di2 < best){ best = di2; bk = k+2; }
        if (di3 < best){ best = di3; bk = k+3; }
      }
      a_loc[t] = bk;
      __syncthreads();
      for (int e=t; e<8*32*33; e+=256) acc8[e] = 0.f;
      cnt8[t] = 0.f;
      __syncthreads();
      {
        const int p0 = oct*32;
        int kcur = a_loc[p0];
        float racc = 0.f; int rl = 0;
        for (int i=0; i<32; ++i){
          int kp = a_loc[p0+i];
          float v = obs_st[(p0+i)*33 + d];
          if (kp != kcur){
            acc8[(oct*32 + kcur)*33 + d] += racc;
            if (d == 0) cnt8[oct*32 + kcur] += (float)rl;
            racc = 0.f; rl = 0; kcur = kp;
          }
          racc += v; ++rl;
        }
        acc8[(oct*32 + kcur)*33 + d] += racc;
        if (d == 0) cnt8[oct*32 + kcur] += (float)rl;
      }
      __syncthreads();
      float* Pg = part + ((size_t)((parity*2 + mb)*SUBS + sub))*1024;
      {
        float r0=0.f, r1=0.f, r2=0.f, r3=0.f;
        #pragma unroll
        for (int o2=0; o2<8; ++o2){
          r0 += acc8[(o2*32 + oct      )*33 + d];
          r1 += acc8[(o2*32 + oct + 8  )*33 + d];
          r2 += acc8[(o2*32 + oct + 16 )*33 + d];
          r3 += acc8[(o2*32 + oct + 24 )*33 + d];
        }
        Pg[(oct     )*32 + d] = r0;
        Pg[(oct + 8 )*32 + d] = r1;
        Pg[(oct + 16)*32 + d] = r2;
        Pg[(oct + 24)*32 + d] = r3;
      }
      if (t < 32){
        float c = 0.f;
        #pragma unroll
        for (int o2=0; o2<8; ++o2) c += cnt8[o2*32 + t];
        cnts[((size_t)((parity*2 + mb)*SUBS + sub))*32 + t] = c;
      }
    }
    gbar2(slots, gen, NWG_KM, it+1);
    for (int bb=0; bb<2; ++bb){
      bool ab = (bb==0) ? act0 : act1;
      if (!ab) continue;
      const float* Pb = part + (size_t)((parity*2 + bb)*SUBS)*1024;
      const float* Cb = cnts + (size_t)((parity*2 + bb)*SUBS)*32;
      if (t < 32){
        float s = 0.f;
        for (int si=0; si<SUBS; ++si) s += Cb[si*32 + t];
        cntsh[t] = s;
      }
      __syncthreads();
      {
        int k = t >> 3, d4 = (t & 7) * 4;
        float4 v = make_float4(0.f, 0.f, 0.f, 0.f);
        for (int si=0; si<SUBS; ++si){
          const float4 p4 = *(const float4*)&Pb[si*1024 + k*32 + d4];
          v.x += p4.x; v.y += p4.y; v.z += p4.z; v.w += p4.w;
        }
        float cn = cntsh[k];
        float den = fmaxf(cn, 1.f);
        bool pos = cn > 0.f;
        float o0 = cent[(bb*32 + k)*32 + d4+0], o1 = cent[(bb*32 + k)*32 + d4+1];
        float o2 = cent[(bb*32 + k)*32 + d4+2], o3 = cent[(bb*32 + k)*32 + d4+3];
        float n0 = pos ? (v.x / den) : o0;
        float n1 = pos ? (v.y / den) : o1;
        float n2 = pos ? (v.z / den) : o2;
        float n3 = pos ? (v.w / den) : o3;
        float e0 = n0-o0, e1 = n1-o1, e2 = n2-o2, e3 = n3-o3;
        sq[k*32 + d4+0] = e0*e0; sq[k*32 + d4+1] = e1*e1;
        sq[k*32 + d4+2] = e2*e2; sq[k*32 + d4+3] = e3*e3;
        cent[(bb*32 + k)*32 + d4+0] = n0; cent[(bb*32 + k)*32 + d4+1] = n1;
        cent[(bb*32 + k)*32 + d4+2] = n2; cent[(bb*32 + k)*32 + d4+3] = n3;
      }
      __syncthreads();
      if (t < 32){
        float s = 0.f;
        #pragma unroll
        for (int dd=0; dd<32; ++dd) s += sq[t*32 + dd];
        snorm[t] = sqrtf(s);
      }
      __syncthreads();
      float sh = 0.f;
      for (int k=0;k<32;++k) sh += snorm[k];
      bool na = ((it+1) < 20) && ((double)sh >= 20.48);
      if (bb==0) act0 = na; else act1 = na;
      __syncthreads();
    }
    parity ^= 1;
  }
  __syncthreads();
  if (t < 32){
    float s = 0.f;
    #pragma unroll
    for (int dd=0; dd<32; ++dd){ float v = cent[(mb*32 + t)*32 + dd]; s = fmaf(v,v,s); }
    cc_s[t] = s;
  }
  __syncthreads();
  float best = 3.0e38f; int bk = 0;
  for (int k=0; k<32; k+=4){
    const float4* c0 = (const float4*)&cent[(mb*32 + k  )*32];
    const float4* c1 = (const float4*)&cent[(mb*32 + k+1)*32];
    const float4* c2 = (const float4*)&cent[(mb*32 + k+2)*32];
    const float4* c3 = (const float4*)&cent[(mb*32 + k+3)*32];
    float dt0=0.f, dt1=0.f, dt2=0.f, dt3=0.f;
    #pragma unroll
    for (int q=0; q<8; ++q){
      float4 a0 = c0[q], a1 = c1[q], a2 = c2[q], a3 = c3[q];
      float o0 = o[q*4+0], o1 = o[q*4+1], o2 = o[q*4+2], o3 = o[q*4+3];
      dt0 = fmaf(o0,a0.x,dt0); dt0 = fmaf(o1,a0.y,dt0); dt0 = fmaf(o2,a0.z,dt0); dt0 = fmaf(o3,a0.w,dt0);
      dt1 = fmaf(o0,a1.x,dt1); dt1 = fmaf(o1,a1.y,dt1); dt1 = fmaf(o2,a1.z,dt1); dt1 = fmaf(o3,a1.w,dt1);
      dt2 = fmaf(o0,a2.x,dt2); dt2 = fmaf(o1,a2.y,dt2); dt2 = fmaf(o2,a2.z,dt2); dt2 = fmaf(o3,a2.w,dt2);
      dt3 = fmaf(o0,a3.x,dt3); dt3 = fmaf(o1,a3.y,dt3); dt3 = fmaf(o2,a3.z,dt3); dt3 = fmaf(o3,a3.w,dt3);
    }
    float di0 = (ss - 2.0f*dt0) + cc_s[k];
    float di1 = (ss - 2.0f*dt1) + cc_s[k+1];
    float di2 = (ss - 2.0f*dt2) + cc_s[k+2];
    float di3 = (ss - 2.0f*dt3) + cc_s[k+3];
    if (di0 < best){ best = di0; bk = k; }
    if (di1 < best){ best = di1; bk = k+1; }
    if (di2 < best){ best = di2; bk = k+2; }
    if (di3 < best){ best = di3; bk = k+3; }
  }
  idxg[mb*PP + pg] = bk;
  st<BF>(dout, (size_t)OUT_ELEMS + mb*PP + pg, (float)bk);
}

__global__ __launch_bounds__(256) void kB(const void* x, float* part, float* cnts,
                                          int* idxg, void* dout,
                                          int* slots, int* gen,
                                          const int* flag, InitIdx ii){
  __shared__ __align__(16) float obs_st[256*33];
  __shared__ __align__(16) float cent[2*32*32];
  __shared__ float cc_s[32];
  __shared__ int   a_loc[256];
  __shared__ float sq[32*32];
  __shared__ float snorm[32];
  __shared__ float cntsh[32];
  __shared__ float acc8[8*32*33];
  __shared__ float cnt8[8*32];
  if (*flag) kB_body<true >(x, part, cnts, idxg, dout, slots, gen, ii,
                            obs_st, cent, cc_s, a_loc, sq, snorm, cntsh, acc8, cnt8);
  else       kB_body<false>(x, part, cnts, idxg, dout, slots, gen, ii,
                            obs_st, cent, cc_s, a_loc, sq, snorm, cntsh, acc8, cnt8);
}

// ---------------- Kernel C v6: tap-parallel coalesced cluster sums (CHANGE UNDER TEST) -----
// grid 288: wg = (b, chunk of 256 pts, tap j in [0,9)). Thread = point (lane<->w:
// coalesced 128B wave-loads), loop c over channel planes, LDS atomicAdd into
// acc[k*33+c] (collisions follow spatial k-runs). Counts from j==0 wgs.
// cpartJ[(cg*9+j)][k*33+c]; order-free reassociation (cpart only feeds MLP path).
template<bool BF>
__device__ void kC_body(const void* __restrict__ x,
                        const int* __restrict__ idxg,
                        float* __restrict__ cpartJ,
                        float* __restrict__ acc,    // [32*33]
                        int* __restrict__ idxsh){   // [256]
  int wgid = blockIdx.x;           // 0..287
  int cg = wgid / 9, j = wgid % 9;
  int b = cg >> 4, pc = cg & 15;
  int t = threadIdx.x;
  for (int e=t; e<32*33; e+=256) acc[e] = 0.f;
  idxsh[t] = idxg[b*PP + pc*256 + t];
  __syncthreads();

  int dh = j/3 - 1, dw = j%3 - 1;
  int gp = (pc << 8) + t;
  int h = gp >> 6, w = gp & 63;
  int k = idxsh[t];
  int hh = h + dh, ww = w + dw;
  bool ok = ((unsigned)hh < 64u) && ((unsigned)ww < 64u);
  size_t boff = ((size_t)b << 17) + (hh << 6) + ww;

  #pragma unroll 4
  for (int c=0; c<32; ++c){
    float v = ok ? ld<BF>(x, boff + ((size_t)c << 12)) : 0.f;
    atomicAdd(&acc[k*33 + c], v);
  }
  if (j == 0) atomicAdd(&acc[k*33 + 32], 1.0f);
  __syncthreads();
  float* cp = cpartJ + (size_t)wgid*(32*33);
  for (int e=t; e<32*33; e+=256) cp[e] = acc[e];
}

__global__ __launch_bounds__(256) void kC(const void* x, const int* idxg,
                                          float* cpartJ, const int* flag){
  __shared__ float acc[32*33];
  __shared__ int   idxsh[256];
  if (*flag) kC_body<true >(x, idxg, cpartJ, acc, idxsh);
  else       kC_body<false>(x, idxg, cpartJ, acc, idxsh);
}

// ---------------- Kernel D: merge cpartJ -> centers + 2 MLPs + softmax ----------------
template<bool BF>
__device__ void kD_body(const float* __restrict__ cpartJ,
                        const void* kg_w1, const void* kg_b1,
                        const void* kg_w2, const void* kg_b2,
                        const void* kg_w3, const void* kg_b3,
                        const void* bg_w1, const void* bg_b1,
                        const void* bg_w2, const void* bg_b2,
                        const void* bg_w3, const void* bg_b3,
                        float* __restrict__ attn,
                        float* __restrict__ biasO,
                        float* __restrict__ row,
                        float* __restrict__ h1,
                        float* __restrict__ h2,
                        float* __restrict__ lgs){
  int wg = blockIdx.x; int b = wg >> 5; int k = wg & 31;
  int t = threadIdx.x;   // 64 threads
  float cnt = 0.f;
  for (int ch=0; ch<16; ++ch)
    cnt += cpartJ[(size_t)((b*16+ch)*9)*(32*33) + k*33 + 32];
  float den = fmaxf(cnt, 1.f);
  for (int f=t; f<FF; f+=64){
    int c = f / 9, j = f % 9;
    float s = 0.f;
    for (int ch=0; ch<16; ++ch)
      s += cpartJ[(size_t)((b*16+ch)*9 + j)*(32*33) + k*33 + c];
    row[f] = s / den;
  }
  __syncthreads();

  {
    float s = 0.f;
    #pragma unroll 8
    for (int f=0; f<FF; ++f) s = fmaf(row[f], ld<BF>(kg_w1, f*HID + t), s);
    h1[t] = fmaxf(s + ld<BF>(kg_b1, t), 0.f);
  }
  __syncthreads();
  {
    float s = 0.f;
    #pragma unroll 8
    for (int h=0; h<HID; ++h) s = fmaf(h1[h], ld<BF>(kg_w2, h*HID + t), s);
    h2[t] = fmaxf(s + ld<BF>(kg_b2, t), 0.f);
  }
  __syncthreads();
  if (t < 32){
    float s = 0.f;
    #pragma unroll 8
    for (int h=0; h<HID; ++h) s = fmaf(h2[h], ld<BF>(kg_w3, h*NBASE + t), s);
    lgs[t] = s + ld<BF>(kg_b3, t);
  }
  __syncthreads();
  if (t < 32){
    float mx = -3.0e38f;
    for (int i=0;i<NBASE;++i) mx = fmaxf(mx, lgs[i]);
    float se = 0.f;
    for (int i=0;i<NBASE;++i) se += expf(lgs[i]-mx);
    attn[wg*NBASE + t] = expf(lgs[t]-mx) / se;
  }
  __syncthreads();
  {
    float s = 0.f;
    #pragma unroll 8
    for (int f=0; f<FF; ++f) s = fmaf(row[f], ld<BF>(bg_w1, f*HID + t), s);
    h1[t] = fmaxf(s + ld<BF>(bg_b1, t), 0.f);
  }
  __syncthreads();
  {
    float s = 0.f;
    #pragma unroll 8
    for (int h=0; h<HID; ++h) s = fmaf(h1[h], ld<BF>(bg_w2, h*HID + t), s);
    h2[t] = fmaxf(s + ld<BF>(bg_b2, t), 0.f);
  }
  __syncthreads();
  {
    float s = 0.f;
    #pragma unroll 8
    for (int h=0; h<HID; ++h) s = fmaf(h2[h], ld<BF>(bg_w3, h*COUT + t), s);
    biasO[wg*COUT + t] = s + ld<BF>(bg_b3, t);
  }
}

__global__ __launch_bounds__(64) void kD(const float* cpartJ,
                                         const void* kg_w1, const void* kg_b1,
                                         const void* kg_w2, const void* kg_b2,
                                         const void* kg_w3, const void* kg_b3,
                                         const void* bg_w1, const void* bg_b1,
                                         const void* bg_w2, const void* bg_b2,
                                         const void* bg_w3, const void* bg_b3,
                                         float* attn, float* biasO, const int* flag){
  __shared__ float row[FF];
  __shared__ float h1[64];
  __shared__ float h2[64];
  __shared__ float lgs[32];
  if (*flag) kD_body<true >(cpartJ, kg_w1,kg_b1,kg_w2,kg_b2,kg_w3,kg_b3,
                            bg_w1,bg_b1,bg_w2,bg_b2,bg_w3,bg_b3, attn, biasO, row,h1,h2,lgs);
  else       kD_body<false>(cpartJ, kg_w1,kg_b1,kg_w2,kg_b2,kg_w3,kg_b3,
                            bg_w1,bg_b1,bg_w2,bg_b2,bg_w3,bg_b3, attn, biasO, row,h1,h2,lgs);
}

// ---------------- Kernel E: Wg[b][k][cout][f] (bf16) = sum_n attn*base (verified) ----------
template<bool BF>
__device__ void kE_body(const void* __restrict__ base,
                        const float* __restrict__ attn,
                        u16* __restrict__ Wg,
                        float* __restrict__ at,
                        float* __restrict__ tile){   // [72][65]
  int wg = blockIdx.x;
  int fq = wg & 3, bk = wg >> 2;
  int t = threadIdx.x;
  if (t < 32) at[t] = attn[bk*NBASE + t];
  __syncthreads();
  int f0 = fq*72;
  for (int e=t; e<72*64; e+=256){
    int fl = e >> 6, c = e & 63;
    size_t bi = (size_t)(f0 + fl)*COUT + c;
    float s = 0.f;
    #pragma unroll 8
    for (int n=0; n<NBASE; ++n)
      s = fmaf(at[n], ld<BF>(base, bi + (size_t)n*FF*COUT), s);
    tile[fl*65 + c] = s;
  }
  __syncthreads();
  for (int e=t; e<72*64; e+=256){
    int c = e / 72, fl = e % 72;
    Wg[(size_t)bk*(64*FF) + (size_t)c*FF + f0 + fl] = f2bf(tile[fl*65 + c]);
  }
}

__global__ __launch_bounds__(256) void kE(const void* base, const float* attn,
                                          u16* Wg, const int* flag){
  __shared__ float at[32];
  __shared__ float tile[72*65];
  if (*flag) kE_body<true >(base, attn, Wg, at, tile);
  else       kE_body<false>(base, attn, Wg, at, tile);
}

// ---------------- Kernel F: conv (R5 structure, verified) ----------------
template<bool BF>
__device__ void kF_body(const void* __restrict__ x,
                        const int* __restrict__ idxg,
                        const u16* __restrict__ Wg,
                        const float* __restrict__ biasO,
                        void* __restrict__ dout,
                        u16* __restrict__ patch,    // [16][296]
                        float* __restrict__ outT){  // [64][17]
  int wg = blockIdx.x;
  int q = wg & 3, h = (wg >> 2) & 63, b = wg >> 8;
  int t = threadIdx.x, wv = t >> 6, lane = t & 63;
  int w0 = q << 4;

  for (int e=t; e<16*FF; e+=256){
    int pl = e & 15, fe = e >> 4;
    int c = fe / 9, j = fe % 9;
    int hh = h + j/3 - 1, ww = w0 + pl + (j%3) - 1;
    float v = 0.f;
    if ((unsigned)hh < 64u && (unsigned)ww < 64u)
      v = ld<BF>(x, ((size_t)b << 17) + ((size_t)c << 12) + (hh<<6) + ww);
    patch[pl*296 + fe] = f2bf(v);
  }
  __syncthreads();

  #pragma unroll
  for (int i=0; i<4; ++i){
    int pl = (wv << 2) + i;
    int p = (h << 6) + w0 + pl;
    int k = idxg[(b << 12) + p];
    const uint4* Wp = (const uint4*)(Wg + ((size_t)((b << 5) + k)*64 + lane)*FF);
    const uint4* Pp = (const uint4*)(patch + pl*296);
    float acc = 0.f;
    #pragma unroll 6
    for (int j=0; j<36; ++j){
      uint4 wv4 = Wp[j];
      uint4 pv4 = Pp[j];
      acc = fmaf(u_lo(pv4.x), u_lo(wv4.x), acc);
      acc = fmaf(u_hi(pv4.x), u_hi(wv4.x), acc);
      acc = fmaf(u_lo(pv4.y), u_lo(wv4.y), acc);
      acc = fmaf(u_hi(pv4.y), u_hi(wv4.y), acc);
      acc = fmaf(u_lo(pv4.z), u_lo(wv4.z), acc);
      acc = fmaf(u_hi(pv4.z), u_hi(wv4.z), acc);
      acc = fmaf(u_lo(pv4.w), u_lo(wv4.w), acc);
      acc = fmaf(u_hi(pv4.w), u_hi(wv4.w), acc);
    }
    float bias = biasO[((b << 5) + k)*COUT + lane];
    outT[lane*17 + pl] = acc + bias;
  }
  __syncthreads();

  for (int e=t; e<1024; e+=256){
    int cout = e >> 4, pl = e & 15;
    st<BF>(dout, (((size_t)(b << 6) + cout) << 12) + (h << 6) + w0 + pl,
           outT[cout*17 + pl]);
  }
}

__global__ __launch_bounds__(256) void kF(const void* x, const int* idxg,
                                          const u16* Wg, const float* biasO,
                                          void* dout, const int* flag){
  __shared__ u16   patch[16*296];
  __shared__ float outT[64*17];
  if (*flag) kF_body<true >(x, idxg, Wg, biasO, dout, patch, outT);
  else       kF_body<false>(x, idxg, Wg, biasO, dout, patch, outT);
}

// ---------------- host: JAX threefry2x32 + permutation(key,4096)[:32] ----------------
static inline uint32_t rotl32(uint32_t x, int d){ return (x<<d)|(x>>(32-d)); }
static void tf_block(uint32_t k0,uint32_t k1,uint32_t x0,uint32_t x1,uint32_t&o0,uint32_t&o1){
  uint32_t ks2 = k0 ^ k1 ^ 0x1BD11BDAu;
  uint32_t v0 = x0 + k0, v1 = x1 + k1;
  const int ra[4]={13,15,26,6}, rb[4]={17,29,16,24};
  #define R4(r) for(int i_=0;i_<4;++i_){ v0 += v1; v1 = rotl32(v1,(r)[i_]); v1 ^= v0; }
  R4(ra); v0 += k1;  v1 += ks2 + 1u;
  R4(rb); v0 += ks2; v1 += k0  + 2u;
  R4(ra); v0 += k0;  v1 += k1  + 3u;
  R4(rb); v0 += k1;  v1 += ks2 + 4u;
  R4(ra); v0 += ks2; v1 += k0  + 5u;
  #undef R4
  o0 = v0; o1 = v1;
}
struct KP{ uint32_t a, b; };
static void tf_split(KP k, KP& first, KP& second){
#if THREEFRY_PARTITIONABLE
  uint32_t a0,b0,a1,b1;
  tf_block(k.a,k.b, 0u,0u, a0,b0);
  tf_block(k.a,k.b, 0u,1u, a1,b1);
  first  = KP{a0,b0};
  second = KP{a1,b1};
#else
  uint32_t a0,b0,a1,b1;
  tf_block(k.a,k.b, 0u,2u, a0,b0);
  tf_block(k.a,k.b, 1u,3u, a1,b1);
  first  = KP{a0,a1};
  second = KP{b0,b1};
#endif
}
static void random_bits_4096(KP k, std::vector<uint32_t>& bits){
#if THREEFRY_PARTITIONABLE
  for (int i=0;i<4096;++i){
    uint32_t o0,o1; tf_block(k.a,k.b, 0u,(uint32_t)i, o0,o1);
    bits[i] = o0 ^ o1;
  }
#else
  for (int i=0;i<2048;++i){
    uint32_t o0,o1; tf_block(k.a,k.b,(uint32_t)i,(uint32_t)(i+2048),o0,o1);
    bits[i] = o0; bits[i+2048] = o1;
  }
#endif
}
static void perm_first32(KP key, int* out32){
  std::vector<int> vals(4096);
  for (int i=0;i<4096;++i) vals[i] = i;
  std::vector<uint32_t> bits(4096);
  std::vector<std::pair<uint32_t,int>> pr(4096);
  KP k = key;
  for (int r=0;r<2;++r){
    KP nk, sk; tf_split(k, nk, sk); k = nk;
    random_bits_4096(sk, bits);
    for (int i=0;i<4096;++i) pr[i] = std::make_pair(bits[i], vals[i]);
    std::stable_sort(pr.begin(), pr.end(),
        [](const std::pair<uint32_t,int>& a, const std::pair<uint32_t,int>& c){ return a.first < c.first; });
    for (int i=0;i<4096;++i) vals[i] = pr[i].second;
  }
  for (int j=0;j<32;++j) out32[j] = vals[j];
}

extern "C" void kernel_launch(void* const* d_in, const int* in_sizes, int n_in,
                              void* d_out, int out_size, void* d_ws, size_t ws_size,
                              hipStream_t stream) {
  const void* x     = d_in[0];
  const void* base  = d_in[1];
  const void* kg_w1 = d_in[2];
  const void* kg_b1 = d_in[3];
  const void* kg_w2 = d_in[4];
  const void* kg_b2 = d_in[5];
  const void* kg_w3 = d_in[6];
  const void* kg_b3 = d_in[7];
  const void* bg_w1 = d_in[8];
  const void* bg_b1 = d_in[9];
  const void* bg_w2 = d_in[10];
  const void* bg_b2 = d_in[11];
  const void* bg_w3 = d_in[12];
  const void* bg_b3 = d_in[13];

  char* ws = (char*)d_ws;
  int*   flag  = (int*)(ws + 64);
  int*   idxg  = (int*)(ws + OFF_IDX);
  float* attn  = (float*)(ws + OFF_ATTN);
  float* biasO = (float*)(ws + OFF_BIAS);
  float* part  = (float*)(ws + OFF_PART);
  float* cnts  = (float*)(ws + OFF_CNTS);
  float* cpartJ= (float*)(ws + OFF_CPART);
  u16*   Wg    = (u16*)(ws + OFF_WG);
  int*   slots = (int*)(ws + OFF_BAR2);
  int*   gen   = (int*)(ws + OFF_BAR2 + 2048);

  InitIdx ii;
  KP root = KP{0u, 42u};
  KP kb0, kb1; tf_split(root, kb0, kb1);
  perm_first32(kb0, ii.v[0]);
  perm_first32(kb1, ii.v[1]);

  hipMemsetAsync(ws + OFF_BAR2, 0, 4096, stream);   // barrier slots + gen

  kDetect<<<1, 256, 0, stream>>>(x, flag);
  kB<<<NWG_KM, 256, 0, stream>>>(x, part, cnts, idxg, d_out, slots, gen, flag, ii);
  kC<<<288, 256, 0, stream>>>(x, idxg, cpartJ, flag);
  kD<<<64, 64, 0, stream>>>(cpartJ,
                            kg_w1, kg_b1, kg_w2, kg_b2, kg_w3, kg_b3,
                            bg_w1, bg_b1, bg_w2, bg_b2, bg_w3, bg_b3,
                            attn, biasO, flag);
  kE<<<256, 256, 0, stream>>>(base, attn, Wg, flag);
  kF<<<512, 256, 0, stream>>>(x, idxg, Wg, biasO, d_out, flag);
}

// Round 17
// 292.170 us; speedup vs baseline: 1.4241x; 1.0240x over previous
//
#include <hip/hip_runtime.h>
#include <hip/hip_bf16.h>
#include <vector>
#include <algorithm>
#include <utility>
#include <stdint.h>

// Problem constants
#define BB 2
#define PP 4096        // H*W
#define FF 288         // C*9
#define KK 32
#define NBASE 32
#define HID 64
#define COUT 64
#define NWG_KM 32      // k-means workgroups (16 per batch)
#define SUBS 16
#define OUT_ELEMS 524288   // 2*64*4096; idx chunk follows

#define THREEFRY_PARTITIONABLE 1

typedef unsigned short u16;

// ---------------- ws layout (bytes) ----------------
// [64..67] dtype flag (written by kDetect)
#define OFF_IDX    512          // 2*4096*4  = 32768
#define OFF_ATTN   33280        // 64*32*4   = 8192
#define OFF_BIAS   41472        // 64*64*4   = 16384
#define OFF_PART   57856        // 4 slots * 16 subs * 1024 f32 = 262144 -> 320000
#define OFF_CNTS   320000       // 4 slots * 16 subs * 32 f32   = 8192   -> 328192
#define OFF_CPART  328192       // 288 wgs * 32 k * 33 f32 = 1216512 -> 1544704
#define OFF_WG     1544704      // 64*64*288 u16 (b,k,cout,f) = 2359296 -> 3904000
#define OFF_BAR2   3904000      // slots 32*16 ints (2048B), zeroed by kDetect

struct InitIdx { int v[2][32]; };

// ---------------- device helpers ----------------
__device__ __forceinline__ float bf2f(u16 u){
  union { unsigned int i; float f; } cv; cv.i = ((unsigned int)u) << 16; return cv.f;
}
__device__ __forceinline__ u16 f2bf(float f){
  union { float f; unsigned int i; } cv; cv.f = f;
  unsigned int x = cv.i;
  unsigned int r = (x + 0x7FFFu + ((x >> 16) & 1u)) >> 16;
  return (u16)r;
}
__device__ __forceinline__ float u_lo(unsigned int u){
  union { unsigned int i; float f; } cv; cv.i = u << 16; return cv.f;
}
__device__ __forceinline__ float u_hi(unsigned int u){
  union { unsigned int i; float f; } cv; cv.i = u & 0xFFFF0000u; return cv.f;
}

template<bool BF>
__device__ __forceinline__ float ld(const void* p, size_t i){
  if constexpr (BF) { return bf2f(((const u16*)p)[i]); }
  else              { return ((const float*)p)[i]; }
}
template<bool BF>
__device__ __forceinline__ void st(void* p, size_t i, float v){
  if constexpr (BF) { ((u16*)p)[i] = f2bf(v); }
  else              { ((float*)p)[i] = v; }
}

template<bool BF>
__device__ __forceinline__ float obs_chan(const void* x, size_t bi, int h, int w){
  float s = 0.f;
  #pragma unroll
  for (int dh=-1; dh<=1; ++dh){
    int hh = h + dh;
    #pragma unroll
    for (int dw=-1; dw<=1; ++dw){
      int ww = w + dw;
      float v = 0.f;
      if ((unsigned)hh < 64u && (unsigned)ww < 64u) v = ld<BF>(x, bi + (hh<<6) + ww);
      s += v;
    }
  }
  return s / 9.0f;
}

// Symmetric per-batch 16-wg barrier: each wg stores its epoch to its own
// cacheline slot; first 16 threads each poll one peer slot. No master, no gen.
// Batches are fully independent (disjoint part/cnts buffers).
__device__ __forceinline__ void gbar16(int* slots, int mb, int sub, int epoch){
  __syncthreads();
  __threadfence();
  const int t = threadIdx.x;
  if (t == 0)
    __hip_atomic_store(&slots[(mb*16 + sub)*16], epoch, __ATOMIC_RELEASE, __HIP_MEMORY_SCOPE_AGENT);
  if (t < 16){
    while (__hip_atomic_load(&slots[(mb*16 + t)*16], __ATOMIC_ACQUIRE, __HIP_MEMORY_SCOPE_AGENT) < epoch){}
  }
  __syncthreads();
  __threadfence();
}

// ---------------- Kernel 0: dtype detection + zero barrier slots ----------------
__global__ __launch_bounds__(256) void kDetect(const void* __restrict__ x, int* flag,
                                               int* slots){
  __shared__ int cnt;
  if (threadIdx.x == 0) cnt = 0;
  // zero 512 ints of barrier slot space
  for (int i = threadIdx.x; i < 512; i += 256) slots[i] = 0;
  __syncthreads();
  const u16* p = (const u16*)x;
  int bad = 0;
  for (int i = threadIdx.x; i < 1024; i += 256){
    u16 u = p[2*i];
    unsigned e = (u >> 7) & 0xFFu;
    if (e >= 131u) ++bad;
  }
  atomicAdd(&cnt, bad);
  __syncthreads();
  if (threadIdx.x == 0) *flag = (cnt < 102) ? 1 : 0;
}

// ---------------- Kernel B: persistent k-means, per-batch independent ----------------
// R15/R16-verified arithmetic (4-way interleaved dots, octant scan, si-order merge)
// restructured so each batch of 16 wgs runs independently: own 16-wg barrier,
// own-batch merge only. Centers/idx bit-identical to R16.
template<bool BF>
__device__ void kB_body(const void* __restrict__ x,
                        float* __restrict__ part,
                        float* __restrict__ cnts,
                        int* __restrict__ idxg,
                        void* __restrict__ dout,
                        int* __restrict__ slots,
                        const InitIdx& ii,
                        float* obs_st,   // [256*33]
                        float* cent,     // [32*32] own batch
                        float* cc_s,     // [32]
                        int*   a_loc,    // [256]
                        float* sq,       // [32*32]
                        float* snorm,    // [32]
                        float* cntsh,    // [32]
                        float* acc8,     // [8*32*33]
                        float* cnt8){    // [8*32]
  const int t   = threadIdx.x;
  const int wg  = blockIdx.x;
  const int mb  = wg >> 4;
  const int sub = wg & 15;
  const int pg  = sub*256 + t;
  const int d   = t & 31, oct = t >> 5;

  float o[32];
  {
    int h = pg >> 6, w = pg & 63;
    size_t xb = (size_t)mb << 17;
    for (int c=0; c<32; ++c){
      float v = obs_chan<BF>(x, xb + ((size_t)c<<12), h, w);
      o[c] = v; obs_st[t*33 + c] = v;
    }
  }
  if (t < 32){
    int q = ii.v[mb][t];
    int qh = q >> 6, qw = q & 63;
    size_t xq = (size_t)mb << 17;
    for (int c=0; c<32; ++c) cent[t*32 + c] = obs_chan<BF>(x, xq + ((size_t)c<<12), qh, qw);
  }
  __syncthreads();

  float ss = 0.f;
  #pragma unroll
  for (int dd=0; dd<32; ++dd) ss = fmaf(o[dd], o[dd], ss);

  bool act = true;
  int parity = 0;

  for (int it=0; it<20 && act; ++it){
    if (t < 32){
      float s = 0.f;
      #pragma unroll
      for (int dd=0; dd<32; ++dd){ float v = cent[t*32 + dd]; s = fmaf(v,v,s); }
      cc_s[t] = s;
    }
    __syncthreads();
    // assignment: 4-way k-interleave; per-k dot order o[0..31] frozen
    float best = 3.0e38f; int bk = 0;
    for (int k=0; k<32; k+=4){
      const float4* c0 = (const float4*)&cent[(k  )*32];
      const float4* c1 = (const float4*)&cent[(k+1)*32];
      const float4* c2 = (const float4*)&cent[(k+2)*32];
      const float4* c3 = (const float4*)&cent[(k+3)*32];
      float dt0=0.f, dt1=0.f, dt2=0.f, dt3=0.f;
      #pragma unroll
      for (int q=0; q<8; ++q){
        float4 a0 = c0[q], a1 = c1[q], a2 = c2[q], a3 = c3[q];
        float o0 = o[q*4+0], o1 = o[q*4+1], o2 = o[q*4+2], o3 = o[q*4+3];
        dt0 = fmaf(o0,a0.x,dt0); dt0 = fmaf(o1,a0.y,dt0); dt0 = fmaf(o2,a0.z,dt0); dt0 = fmaf(o3,a0.w,dt0);
        dt1 = fmaf(o0,a1.x,dt1); dt1 = fmaf(o1,a1.y,dt1); dt1 = fmaf(o2,a1.z,dt1); dt1 = fmaf(o3,a1.w,dt1);
        dt2 = fmaf(o0,a2.x,dt2); dt2 = fmaf(o1,a2.y,dt2); dt2 = fmaf(o2,a2.z,dt2); dt2 = fmaf(o3,a2.w,dt2);
        dt3 = fmaf(o0,a3.x,dt3); dt3 = fmaf(o1,a3.y,dt3); dt3 = fmaf(o2,a3.z,dt3); dt3 = fmaf(o3,a3.w,dt3);
      }
      float di0 = (ss - 2.0f*dt0) + cc_s[k];
      float di1 = (ss - 2.0f*dt1) + cc_s[k+1];
      float di2 = (ss - 2.0f*dt2) + cc_s[k+2];
      float di3 = (ss - 2.0f*dt3) + cc_s[k+3];
      if (di0 < best){ best = di0; bk = k; }
      if (di1 < best){ best = di1; bk = k+1; }
      if (di2 < best){ best = di2; bk = k+2; }
      if (di3 < best){ best = di3; bk = k+3; }
    }
    a_loc[t] = bk;
    __syncthreads();
    for (int e=t; e<8*32*33; e+=256) acc8[e] = 0.f;
    cnt8[t] = 0.f;
    __syncthreads();
    {
      const int p0 = oct*32;
      int kcur = a_loc[p0];
      float racc = 0.f; int rl = 0;
      for (int i=0; i<32; ++i){
        int kp = a_loc[p0+i];
        float v = obs_st[(p0+i)*33 + d];
        if (kp != kcur){
          acc8[(oct*32 + kcur)*33 + d] += racc;
          if (d == 0) cnt8[oct*32 + kcur] += (float)rl;
          racc = 0.f; rl = 0; kcur = kp;
        }
        racc += v; ++rl;
      }
      acc8[(oct*32 + kcur)*33 + d] += racc;
      if (d == 0) cnt8[oct*32 + kcur] += (float)rl;
    }
    __syncthreads();
    float* Pg = part + ((size_t)((parity*2 + mb)*SUBS + sub))*1024;
    {
      float r0=0.f, r1=0.f, r2=0.f, r3=0.f;
      #pragma unroll
      for (int o2=0; o2<8; ++o2){
        r0 += acc8[(o2*32 + oct      )*33 + d];
        r1 += acc8[(o2*32 + oct + 8  )*33 + d];
        r2 += acc8[(o2*32 + oct + 16 )*33 + d];
        r3 += acc8[(o2*32 + oct + 24 )*33 + d];
      }
      Pg[(oct     )*32 + d] = r0;
      Pg[(oct + 8 )*32 + d] = r1;
      Pg[(oct + 16)*32 + d] = r2;
      Pg[(oct + 24)*32 + d] = r3;
    }
    if (t < 32){
      float c = 0.f;
      #pragma unroll
      for (int o2=0; o2<8; ++o2) c += cnt8[o2*32 + t];
      cnts[((size_t)((parity*2 + mb)*SUBS + sub))*32 + t] = c;
    }
    gbar16(slots, mb, sub, it+1);
    // merge own batch only (si order 0..15 frozen)
    {
      const float* Pb = part + (size_t)((parity*2 + mb)*SUBS)*1024;
      const float* Cb = cnts + (size_t)((parity*2 + mb)*SUBS)*32;
      if (t < 32){
        float s = 0.f;
        for (int si=0; si<SUBS; ++si) s += Cb[si*32 + t];
        cntsh[t] = s;
      }
      __syncthreads();
      {
        int k = t >> 3, d4 = (t & 7) * 4;
        float4 v = make_float4(0.f, 0.f, 0.f, 0.f);
        for (int si=0; si<SUBS; ++si){
          const float4 p4 = *(const float4*)&Pb[si*1024 + k*32 + d4];
          v.x += p4.x; v.y += p4.y; v.z += p4.z; v.w += p4.w;
        }
        float cn = cntsh[k];
        float den = fmaxf(cn, 1.f);
        bool pos = cn > 0.f;
        float o0 = cent[k*32 + d4+0], o1 = cent[k*32 + d4+1];
        float o2 = cent[k*32 + d4+2], o3 = cent[k*32 + d4+3];
        float n0 = pos ? (v.x / den) : o0;
        float n1 = pos ? (v.y / den) : o1;
        float n2 = pos ? (v.z / den) : o2;
        float n3 = pos ? (v.w / den) : o3;
        float e0 = n0-o0, e1 = n1-o1, e2 = n2-o2, e3 = n3-o3;
        sq[k*32 + d4+0] = e0*e0; sq[k*32 + d4+1] = e1*e1;
        sq[k*32 + d4+2] = e2*e2; sq[k*32 + d4+3] = e3*e3;
        cent[k*32 + d4+0] = n0; cent[k*32 + d4+1] = n1;
        cent[k*32 + d4+2] = n2; cent[k*32 + d4+3] = n3;
      }
      __syncthreads();
      if (t < 32){
        float s = 0.f;
        #pragma unroll
        for (int dd=0; dd<32; ++dd) s += sq[t*32 + dd];
        snorm[t] = sqrtf(s);
      }
      __syncthreads();
      float sh = 0.f;
      for (int k=0;k<32;++k) sh += snorm[k];
      act = ((it+1) < 20) && ((double)sh >= 20.48);
      __syncthreads();
    }
    parity ^= 1;
  }
  // release peers (polls use < epoch; INT_MAX passes all future epochs)
  if (t == 0)
    __hip_atomic_store(&slots[(mb*16 + sub)*16], 0x7FFFFFFF, __ATOMIC_RELEASE, __HIP_MEMORY_SCOPE_AGENT);
  __syncthreads();
  if (t < 32){
    float s = 0.f;
    #pragma unroll
    for (int dd=0; dd<32; ++dd){ float v = cent[t*32 + dd]; s = fmaf(v,v,s); }
    cc_s[t] = s;
  }
  __syncthreads();
  float best = 3.0e38f; int bk = 0;
  for (int k=0; k<32; k+=4){
    const float4* c0 = (const float4*)&cent[(k  )*32];
    const float4* c1 = (const float4*)&cent[(k+1)*32];
    const float4* c2 = (const float4*)&cent[(k+2)*32];
    const float4* c3 = (const float4*)&cent[(k+3)*32];
    float dt0=0.f, dt1=0.f, dt2=0.f, dt3=0.f;
    #pragma unroll
    for (int q=0; q<8; ++q){
      float4 a0 = c0[q], a1 = c1[q], a2 = c2[q], a3 = c3[q];
      float o0 = o[q*4+0], o1 = o[q*4+1], o2 = o[q*4+2], o3 = o[q*4+3];
      dt0 = fmaf(o0,a0.x,dt0); dt0 = fmaf(o1,a0.y,dt0); dt0 = fmaf(o2,a0.z,dt0); dt0 = fmaf(o3,a0.w,dt0);
      dt1 = fmaf(o0,a1.x,dt1); dt1 = fmaf(o1,a1.y,dt1); dt1 = fmaf(o2,a1.z,dt1); dt1 = fmaf(o3,a1.w,dt1);
      dt2 = fmaf(o0,a2.x,dt2); dt2 = fmaf(o1,a2.y,dt2); dt2 = fmaf(o2,a2.z,dt2); dt2 = fmaf(o3,a2.w,dt2);
      dt3 = fmaf(o0,a3.x,dt3); dt3 = fmaf(o1,a3.y,dt3); dt3 = fmaf(o2,a3.z,dt3); dt3 = fmaf(o3,a3.w,dt3);
    }
    float di0 = (ss - 2.0f*dt0) + cc_s[k];
    float di1 = (ss - 2.0f*dt1) + cc_s[k+1];
    float di2 = (ss - 2.0f*dt2) + cc_s[k+2];
    float di3 = (ss - 2.0f*dt3) + cc_s[k+3];
    if (di0 < best){ best = di0; bk = k; }
    if (di1 < best){ best = di1; bk = k+1; }
    if (di2 < best){ best = di2; bk = k+2; }
    if (di3 < best){ best = di3; bk = k+3; }
  }
  idxg[mb*PP + pg] = bk;
  st<BF>(dout, (size_t)OUT_ELEMS + mb*PP + pg, (float)bk);
}

__global__ __launch_bounds__(256) void kB(const void* x, float* part, float* cnts,
                                          int* idxg, void* dout,
                                          int* slots,
                                          const int* flag, InitIdx ii){
  __shared__ __align__(16) float obs_st[256*33];
  __shared__ __align__(16) float cent[32*32];
  __shared__ float cc_s[32];
  __shared__ int   a_loc[256];
  __shared__ float sq[32*32];
  __shared__ float snorm[32];
  __shared__ float cntsh[32];
  __shared__ float acc8[8*32*33];
  __shared__ float cnt8[8*32];
  if (*flag) kB_body<true >(x, part, cnts, idxg, dout, slots, ii,
                            obs_st, cent, cc_s, a_loc, sq, snorm, cntsh, acc8, cnt8);
  else       kB_body<false>(x, part, cnts, idxg, dout, slots, ii,
                            obs_st, cent, cc_s, a_loc, sq, snorm, cntsh, acc8, cnt8);
}

// ---------------- Kernel C v6: tap-parallel coalesced cluster sums (R16-verified) ----------
template<bool BF>
__device__ void kC_body(const void* __restrict__ x,
                        const int* __restrict__ idxg,
                        float* __restrict__ cpartJ,
                        float* __restrict__ acc,    // [32*33]
                        int* __restrict__ idxsh){   // [256]
  int wgid = blockIdx.x;           // 0..287
  int cg = wgid / 9, j = wgid % 9;
  int b = cg >> 4, pc = cg & 15;
  int t = threadIdx.x;
  for (int e=t; e<32*33; e+=256) acc[e] = 0.f;
  idxsh[t] = idxg[b*PP + pc*256 + t];
  __syncthreads();

  int dh = j/3 - 1, dw = j%3 - 1;
  int gp = (pc << 8) + t;
  int h = gp >> 6, w = gp & 63;
  int k = idxsh[t];
  int hh = h + dh, ww = w + dw;
  bool ok = ((unsigned)hh < 64u) && ((unsigned)ww < 64u);
  size_t boff = ((size_t)b << 17) + (hh << 6) + ww;

  #pragma unroll 4
  for (int c=0; c<32; ++c){
    float v = ok ? ld<BF>(x, boff + ((size_t)c << 12)) : 0.f;
    atomicAdd(&acc[k*33 + c], v);
  }
  if (j == 0) atomicAdd(&acc[k*33 + 32], 1.0f);
  __syncthreads();
  float* cp = cpartJ + (size_t)wgid*(32*33);
  for (int e=t; e<32*33; e+=256) cp[e] = acc[e];
}

__global__ __launch_bounds__(256) void kC(const void* x, const int* idxg,
                                          float* cpartJ, const int* flag){
  __shared__ float acc[32*33];
  __shared__ int   idxsh[256];
  if (*flag) kC_body<true >(x, idxg, cpartJ, acc, idxsh);
  else       kC_body<false>(x, idxg, cpartJ, acc, idxsh);
}

// ---------------- Kernel D: merge cpartJ -> centers + 2 MLPs + softmax (R16-verified) ------
template<bool BF>
__device__ void kD_body(const float* __restrict__ cpartJ,
                        const void* kg_w1, const void* kg_b1,
                        const void* kg_w2, const void* kg_b2,
                        const void* kg_w3, const void* kg_b3,
                        const void* bg_w1, const void* bg_b1,
                        const void* bg_w2, const void* bg_b2,
                        const void* bg_w3, const void* bg_b3,
                        float* __restrict__ attn,
                        float* __restrict__ biasO,
                        float* __restrict__ row,
                        float* __restrict__ h1,
                        float* __restrict__ h2,
                        float* __restrict__ lgs){
  int wg = blockIdx.x; int b = wg >> 5; int k = wg & 31;
  int t = threadIdx.x;   // 64 threads
  float cnt = 0.f;
  for (int ch=0; ch<16; ++ch)
    cnt += cpartJ[(size_t)((b*16+ch)*9)*(32*33) + k*33 + 32];
  float den = fmaxf(cnt, 1.f);
  for (int f=t; f<FF; f+=64){
    int c = f / 9, j = f % 9;
    float s = 0.f;
    for (int ch=0; ch<16; ++ch)
      s += cpartJ[(size_t)((b*16+ch)*9 + j)*(32*33) + k*33 + c];
    row[f] = s / den;
  }
  __syncthreads();

  {
    float s = 0.f;
    #pragma unroll 8
    for (int f=0; f<FF; ++f) s = fmaf(row[f], ld<BF>(kg_w1, f*HID + t), s);
    h1[t] = fmaxf(s + ld<BF>(kg_b1, t), 0.f);
  }
  __syncthreads();
  {
    float s = 0.f;
    #pragma unroll 8
    for (int h=0; h<HID; ++h) s = fmaf(h1[h], ld<BF>(kg_w2, h*HID + t), s);
    h2[t] = fmaxf(s + ld<BF>(kg_b2, t), 0.f);
  }
  __syncthreads();
  if (t < 32){
    float s = 0.f;
    #pragma unroll 8
    for (int h=0; h<HID; ++h) s = fmaf(h2[h], ld<BF>(kg_w3, h*NBASE + t), s);
    lgs[t] = s + ld<BF>(kg_b3, t);
  }
  __syncthreads();
  if (t < 32){
    float mx = -3.0e38f;
    for (int i=0;i<NBASE;++i) mx = fmaxf(mx, lgs[i]);
    float se = 0.f;
    for (int i=0;i<NBASE;++i) se += expf(lgs[i]-mx);
    attn[wg*NBASE + t] = expf(lgs[t]-mx) / se;
  }
  __syncthreads();
  {
    float s = 0.f;
    #pragma unroll 8
    for (int f=0; f<FF; ++f) s = fmaf(row[f], ld<BF>(bg_w1, f*HID + t), s);
    h1[t] = fmaxf(s + ld<BF>(bg_b1, t), 0.f);
  }
  __syncthreads();
  {
    float s = 0.f;
    #pragma unroll 8
    for (int h=0; h<HID; ++h) s = fmaf(h1[h], ld<BF>(bg_w2, h*HID + t), s);
    h2[t] = fmaxf(s + ld<BF>(bg_b2, t), 0.f);
  }
  __syncthreads();
  {
    float s = 0.f;
    #pragma unroll 8
    for (int h=0; h<HID; ++h) s = fmaf(h2[h], ld<BF>(bg_w3, h*COUT + t), s);
    biasO[wg*COUT + t] = s + ld<BF>(bg_b3, t);
  }
}

__global__ __launch_bounds__(64) void kD(const float* cpartJ,
                                         const void* kg_w1, const void* kg_b1,
                                         const void* kg_w2, const void* kg_b2,
                                         const void* kg_w3, const void* kg_b3,
                                         const void* bg_w1, const void* bg_b1,
                                         const void* bg_w2, const void* bg_b2,
                                         const void* bg_w3, const void* bg_b3,
                                         float* attn, float* biasO, const int* flag){
  __shared__ float row[FF];
  __shared__ float h1[64];
  __shared__ float h2[64];
  __shared__ float lgs[32];
  if (*flag) kD_body<true >(cpartJ, kg_w1,kg_b1,kg_w2,kg_b2,kg_w3,kg_b3,
                            bg_w1,bg_b1,bg_w2,bg_b2,bg_w3,bg_b3, attn, biasO, row,h1,h2,lgs);
  else       kD_body<false>(cpartJ, kg_w1,kg_b1,kg_w2,kg_b2,kg_w3,kg_b3,
                            bg_w1,bg_b1,bg_w2,bg_b2,bg_w3,bg_b3, attn, biasO, row,h1,h2,lgs);
}

// ---------------- Kernel E: Wg[b][k][cout][f] (bf16) = sum_n attn*base (verified) ----------
template<bool BF>
__device__ void kE_body(const void* __restrict__ base,
                        const float* __restrict__ attn,
                        u16* __restrict__ Wg,
                        float* __restrict__ at,
                        float* __restrict__ tile){   // [72][65]
  int wg = blockIdx.x;
  int fq = wg & 3, bk = wg >> 2;
  int t = threadIdx.x;
  if (t < 32) at[t] = attn[bk*NBASE + t];
  __syncthreads();
  int f0 = fq*72;
  for (int e=t; e<72*64; e+=256){
    int fl = e >> 6, c = e & 63;
    size_t bi = (size_t)(f0 + fl)*COUT + c;
    float s = 0.f;
    #pragma unroll 8
    for (int n=0; n<NBASE; ++n)
      s = fmaf(at[n], ld<BF>(base, bi + (size_t)n*FF*COUT), s);
    tile[fl*65 + c] = s;
  }
  __syncthreads();
  for (int e=t; e<72*64; e+=256){
    int c = e / 72, fl = e % 72;
    Wg[(size_t)bk*(64*FF) + (size_t)c*FF + f0 + fl] = f2bf(tile[fl*65 + c]);
  }
}

__global__ __launch_bounds__(256) void kE(const void* base, const float* attn,
                                          u16* Wg, const int* flag){
  __shared__ float at[32];
  __shared__ float tile[72*65];
  if (*flag) kE_body<true >(base, attn, Wg, at, tile);
  else       kE_body<false>(base, attn, Wg, at, tile);
}

// ---------------- Kernel F: conv (R5 structure, verified) ----------------
template<bool BF>
__device__ void kF_body(const void* __restrict__ x,
                        const int* __restrict__ idxg,
                        const u16* __restrict__ Wg,
                        const float* __restrict__ biasO,
                        void* __restrict__ dout,
                        u16* __restrict__ patch,    // [16][296]
                        float* __restrict__ outT){  // [64][17]
  int wg = blockIdx.x;
  int q = wg & 3, h = (wg >> 2) & 63, b = wg >> 8;
  int t = threadIdx.x, wv = t >> 6, lane = t & 63;
  int w0 = q << 4;

  for (int e=t; e<16*FF; e+=256){
    int pl = e & 15, fe = e >> 4;
    int c = fe / 9, j = fe % 9;
    int hh = h + j/3 - 1, ww = w0 + pl + (j%3) - 1;
    float v = 0.f;
    if ((unsigned)hh < 64u && (unsigned)ww < 64u)
      v = ld<BF>(x, ((size_t)b << 17) + ((size_t)c << 12) + (hh<<6) + ww);
    patch[pl*296 + fe] = f2bf(v);
  }
  __syncthreads();

  #pragma unroll
  for (int i=0; i<4; ++i){
    int pl = (wv << 2) + i;
    int p = (h << 6) + w0 + pl;
    int k = idxg[(b << 12) + p];
    const uint4* Wp = (const uint4*)(Wg + ((size_t)((b << 5) + k)*64 + lane)*FF);
    const uint4* Pp = (const uint4*)(patch + pl*296);
    float acc = 0.f;
    #pragma unroll 6
    for (int j=0; j<36; ++j){
      uint4 wv4 = Wp[j];
      uint4 pv4 = Pp[j];
      acc = fmaf(u_lo(pv4.x), u_lo(wv4.x), acc);
      acc = fmaf(u_hi(pv4.x), u_hi(wv4.x), acc);
      acc = fmaf(u_lo(pv4.y), u_lo(wv4.y), acc);
      acc = fmaf(u_hi(pv4.y), u_hi(wv4.y), acc);
      acc = fmaf(u_lo(pv4.z), u_lo(wv4.z), acc);
      acc = fmaf(u_hi(pv4.z), u_hi(wv4.z), acc);
      acc = fmaf(u_lo(pv4.w), u_lo(wv4.w), acc);
      acc = fmaf(u_hi(pv4.w), u_hi(wv4.w), acc);
    }
    float bias = biasO[((b << 5) + k)*COUT + lane];
    outT[lane*17 + pl] = acc + bias;
  }
  __syncthreads();

  for (int e=t; e<1024; e+=256){
    int cout = e >> 4, pl = e & 15;
    st<BF>(dout, (((size_t)(b << 6) + cout) << 12) + (h << 6) + w0 + pl,
           outT[cout*17 + pl]);
  }
}

__global__ __launch_bounds__(256) void kF(const void* x, const int* idxg,
                                          const u16* Wg, const float* biasO,
                                          void* dout, const int* flag){
  __shared__ u16   patch[16*296];
  __shared__ float outT[64*17];
  if (*flag) kF_body<true >(x, idxg, Wg, biasO, dout, patch, outT);
  else       kF_body<false>(x, idxg, Wg, biasO, dout, patch, outT);
}

// ---------------- host: JAX threefry2x32 + permutation(key,4096)[:32] ----------------
static inline uint32_t rotl32(uint32_t x, int d){ return (x<<d)|(x>>(32-d)); }
static void tf_block(uint32_t k0,uint32_t k1,uint32_t x0,uint32_t x1,uint32_t&o0,uint32_t&o1){
  uint32_t ks2 = k0 ^ k1 ^ 0x1BD11BDAu;
  uint32_t v0 = x0 + k0, v1 = x1 + k1;
  const int ra[4]={13,15,26,6}, rb[4]={17,29,16,24};
  #define R4(r) for(int i_=0;i_<4;++i_){ v0 += v1; v1 = rotl32(v1,(r)[i_]); v1 ^= v0; }
  R4(ra); v0 += k1;  v1 += ks2 + 1u;
  R4(rb); v0 += ks2; v1 += k0  + 2u;
  R4(ra); v0 += k0;  v1 += k1  + 3u;
  R4(rb); v0 += k1;  v1 += ks2 + 4u;
  R4(ra); v0 += ks2; v1 += k0  + 5u;
  #undef R4
  o0 = v0; o1 = v1;
}
struct KP{ uint32_t a, b; };
static void tf_split(KP k, KP& first, KP& second){
#if THREEFRY_PARTITIONABLE
  uint32_t a0,b0,a1,b1;
  tf_block(k.a,k.b, 0u,0u, a0,b0);
  tf_block(k.a,k.b, 0u,1u, a1,b1);
  first  = KP{a0,b0};
  second = KP{a1,b1};
#else
  uint32_t a0,b0,a1,b1;
  tf_block(k.a,k.b, 0u,2u, a0,b0);
  tf_block(k.a,k.b, 1u,3u, a1,b1);
  first  = KP{a0,a1};
  second = KP{b0,b1};
#endif
}
static void random_bits_4096(KP k, std::vector<uint32_t>& bits){
#if THREEFRY_PARTITIONABLE
  for (int i=0;i<4096;++i){
    uint32_t o0,o1; tf_block(k.a,k.b, 0u,(uint32_t)i, o0,o1);
    bits[i] = o0 ^ o1;
  }
#else
  for (int i=0;i<2048;++i){
    uint32_t o0,o1; tf_block(k.a,k.b,(uint32_t)i,(uint32_t)(i+2048),o0,o1);
    bits[i] = o0; bits[i+2048] = o1;
  }
#endif
}
static void perm_first32(KP key, int* out32){
  std::vector<int> vals(4096);
  for (int i=0;i<4096;++i) vals[i] = i;
  std::vector<uint32_t> bits(4096);
  std::vector<std::pair<uint32_t,int>> pr(4096);
  KP k = key;
  for (int r=0;r<2;++r){
    KP nk, sk; tf_split(k, nk, sk); k = nk;
    random_bits_4096(sk, bits);
    for (int i=0;i<4096;++i) pr[i] = std::make_pair(bits[i], vals[i]);
    std::stable_sort(pr.begin(), pr.end(),
        [](const std::pair<uint32_t,int>& a, const std::pair<uint32_t,int>& c){ return a.first < c.first; });
    for (int i=0;i<4096;++i) vals[i] = pr[i].second;
  }
  for (int j=0;j<32;++j) out32[j] = vals[j];
}

extern "C" void kernel_launch(void* const* d_in, const int* in_sizes, int n_in,
                              void* d_out, int out_size, void* d_ws, size_t ws_size,
                              hipStream_t stream) {
  const void* x     = d_in[0];
  const void* base  = d_in[1];
  const void* kg_w1 = d_in[2];
  const void* kg_b1 = d_in[3];
  const void* kg_w2 = d_in[4];
  const void* kg_b2 = d_in[5];
  const void* kg_w3 = d_in[6];
  const void* kg_b3 = d_in[7];
  const void* bg_w1 = d_in[8];
  const void* bg_b1 = d_in[9];
  const void* bg_w2 = d_in[10];
  const void* bg_b2 = d_in[11];
  const void* bg_w3 = d_in[12];
  const void* bg_b3 = d_in[13];

  char* ws = (char*)d_ws;
  int*   flag  = (int*)(ws + 64);
  int*   idxg  = (int*)(ws + OFF_IDX);
  float* attn  = (float*)(ws + OFF_ATTN);
  float* biasO = (float*)(ws + OFF_BIAS);
  float* part  = (float*)(ws + OFF_PART);
  float* cnts  = (float*)(ws + OFF_CNTS);
  float* cpartJ= (float*)(ws + OFF_CPART);
  u16*   Wg    = (u16*)(ws + OFF_WG);
  int*   slots = (int*)(ws + OFF_BAR2);

  InitIdx ii;
  KP root = KP{0u, 42u};
  KP kb0, kb1; tf_split(root, kb0, kb1);
  perm_first32(kb0, ii.v[0]);
  perm_first32(kb1, ii.v[1]);

  kDetect<<<1, 256, 0, stream>>>(x, flag, slots);
  kB<<<NWG_KM, 256, 0, stream>>>(x, part, cnts, idxg, d_out, slots, flag, ii);
  kC<<<288, 256, 0, stream>>>(x, idxg, cpartJ, flag);
  kD<<<64, 64, 0, stream>>>(cpartJ,
                            kg_w1, kg_b1, kg_w2, kg_b2, kg_w3, kg_b3,
                            bg_w1, bg_b1, bg_w2, bg_b2, bg_w3, bg_b3,
                            attn, biasO, flag);
  kE<<<256, 256, 0, stream>>>(base, attn, Wg, flag);
  kF<<<512, 256, 0, stream>>>(x, idxg, Wg, biasO, d_out, flag);
}